// Round 7
// baseline (4029.954 us; speedup 1.0000x reference)
//
#include <hip/hip_runtime.h>
#include <math.h>

#define NRAYS 16384
#define NC    64
#define NF    128
#define NZ    192   // NC + NF
#define H     64

__device__ __forceinline__ float wave_incl_scan(float v, int lane) {
#pragma unroll
  for (int off = 1; off < 64; off <<= 1) {
    float n = __shfl_up(v, off);
    v = (lane >= off) ? v + n : v;
  }
  return v;
}

// Exact running max (order-insensitive) — forces the CDF non-decreasing
// despite fp non-associativity of the shuffle +-scan.
__device__ __forceinline__ float wave_incl_max_scan(float v, int lane) {
#pragma unroll
  for (int off = 1; off < 64; off <<= 1) {
    float n = __shfl_up(v, off);
    v = (lane >= off) ? fmaxf(v, n) : v;
  }
  return v;
}

__device__ __forceinline__ float wave_sum(float v) {
#pragma unroll
  for (int off = 32; off > 0; off >>= 1) v += __shfl_xor(v, off);
  return v;
}

// Small wave-uniform weights staged in LDS (broadcast reads, cheap).
// W2 (64x64) is read straight from global with wave-uniform addresses ->
// scalar loads (SGPR broadcast), keeping it off the LDS pipe.
struct __align__(16) WLds {
  float W1b[H][4];   // {w1[0][j], w1[1][j], w1[2][j], b1[j]}
  float B2[H];
  float Head[H][4];  // {wr[j][0..2], wd[j]}
};

__device__ __forceinline__ void load_weights_lds(
    int tid,
    const float* __restrict__ w1, const float* __restrict__ b1,
    const float* __restrict__ b2,
    const float* __restrict__ wr, const float* __restrict__ wd,
    WLds& W)
{
  if (tid < H) {
    int j = tid;
    W.W1b[j][0] = w1[0*H + j];
    W.W1b[j][1] = w1[1*H + j];
    W.W1b[j][2] = w1[2*H + j];
    W.W1b[j][3] = b1[j];
    W.B2[j]     = b2[j];
    W.Head[j][0] = wr[j*3 + 0];
    W.Head[j][1] = wr[j*3 + 1];
    W.Head[j][2] = wr[j*3 + 2];
    W.Head[j][3] = wd[j];
  }
}

// Per-lane full MLP in TWO j-chunks of 32 (acc[32] -> SROA to registers).
// k-loop unroll is 2 (NOT 4/8): the wave-uniform w2 row values live in
// SGPRs; unroll N needs 32*N floats of SGPR space and the file is ~102.
// R5 (unroll 8) and R6 (unroll 4) both triggered SGPR->VGPR->scratch spill
// cascades (533MB-1.8GB of scratch writes). unroll 2 = 64 live floats: fits.
__device__ __forceinline__ void mlp_eval(
    float x0, float x1, float x2, const WLds& W,
    const float* __restrict__ w2,
    float hb0, float hb1, float hb2, float hbd,
    float& r0o, float& r1o, float& r2o, float& dno)
{
  float r0 = hb0, r1 = hb1, r2 = hb2, dn = hbd;
#pragma unroll
  for (int jc = 0; jc < 2; ++jc) {
    const int jbase = jc * 32;
    float acc[32];
#pragma unroll
    for (int i = 0; i < 32; ++i) acc[i] = W.B2[jbase + i];
#pragma unroll 2
    for (int k = 0; k < H; ++k) {
      const float4 wv = *(const float4*)(&W.W1b[k][0]);
      const float h1k =
          fmaxf(fmaf(x0, wv.x, fmaf(x1, wv.y, fmaf(x2, wv.z, wv.w))), 0.f);
      const float* __restrict__ wrow = w2 + k * H + jbase;  // uniform address
#pragma unroll
      for (int i = 0; i < 32; ++i) acc[i] = fmaf(h1k, wrow[i], acc[i]);
    }
#pragma unroll
    for (int i = 0; i < 32; ++i) {
      const float h2v = fmaxf(acc[i], 0.f);
      const float4 hw = *(const float4*)(&W.Head[jbase + i][0]);
      r0 = fmaf(h2v, hw.x, r0);
      r1 = fmaf(h2v, hw.y, r1);
      r2 = fmaf(h2v, hw.z, r2);
      dn = fmaf(h2v, hw.w, dn);
    }
  }
  r0o = 1.f / (1.f + expf(-r0));
  r1o = 1.f / (1.f + expf(-r1));
  r2o = 1.f / (1.f + expf(-r2));
  dno = fmaxf(dn, 0.f);
}

// Coarse pass for one ray, executed by ONE wave (no block barriers inside!).
// Writes the merged 192-entry z row into zdst (LDS). If emit, writes the
// coarse half of this ray's output row. Scratch arrays are wave-private LDS.
__device__ __forceinline__ void coarse_pass(
    int ray, int lane,
    const float* __restrict__ origins, const float* __restrict__ dirs,
    const float* __restrict__ nearp, const float* __restrict__ farp,
    const float* __restrict__ bkgd,
    const WLds& W, const float* __restrict__ w2,
    float hb0, float hb1, float hb2, float hbd,
    float* __restrict__ sT, float* __restrict__ sBins,
    float* __restrict__ sCdf, float* __restrict__ sZs,
    float* __restrict__ zdst, bool emit, float* __restrict__ out)
{
  const float nearv = nearp[ray];
  const float farv  = farp[ray];
  const float ox = origins[ray*3+0], oy = origins[ray*3+1], oz = origins[ray*3+2];
  const float dx = dirs[ray*3+0],    dy = dirs[ray*3+1],    dz = dirs[ray*3+2];

  // exact linspace endpoints: u = lane/63
  const float u_i  = (float)lane / 63.0f;
  const float u_n  = (float)(lane + 1) / 63.0f;
  const float tv    = nearv * (1.f - u_i) + farv * u_i;
  const float tnext = nearv * (1.f - u_n) + farv * u_n;

  sT[lane] = tv;
  if (lane < NC-1) sBins[lane] = 0.5f * (tv + tnext);
  // defensively zero the merge destination (bijective merge should cover all)
  zdst[lane] = 0.f; zdst[lane+64] = 0.f; zdst[lane+128] = 0.f;

  float rgb0, rgb1, rgb2, dens;
  mlp_eval(ox + tv*dx, oy + tv*dy, oz + tv*dz, W, w2, hb0, hb1, hb2, hbd,
           rgb0, rgb1, rgb2, dens);

  const float dnorm = sqrtf(dx*dx + dy*dy + dz*dz);
  const float tdist = (lane == NC-1) ? 1e10f : (tnext - tv);
  // clamp: exp(-1e4)==exp(-anything bigger)==0 in fp32; prevents inf-inf NaN
  const float dd    = fminf(dens * (tdist * dnorm), 1e4f);
  const float incl  = wave_incl_scan(dd, lane);
  const float excl  = incl - dd;
  const float alpha = 1.f - expf(-dd);
  const float trans = expf(-excl);
  const float w     = alpha * trans;

  if (emit) {
    // ray-0 t_vals for the samples[0] quirk in pts0
    const float near0 = nearp[0], far0 = farp[0];
    const float t0v   = near0 * (1.f - u_i) + far0 * u_i;
    const float s_w   = wave_sum(w);
    const float s_wt  = wave_sum(w * tv);
    const float s_c0  = wave_sum(w * rgb0);
    const float s_c1  = wave_sum(w * rgb1);
    const float s_c2  = wave_sum(w * rgb2);
    const float s_wt0 = wave_sum(w * t0v);
    if (lane == 0) {
      const float bk0 = bkgd[0], bk1 = bkgd[1], bk2 = bkgd[2];
      const float o0x = origins[0], o0y = origins[1], o0z = origins[2];
      const float d0x = dirs[0],    d0y = dirs[1],    d0z = dirs[2];
      const float oma = 1.f - s_w;
      float* o = out + (size_t)ray * 16;
      o[0] = s_c0 + bk0 * oma;
      o[1] = s_c1 + bk1 * oma;
      o[2] = s_c2 + bk2 * oma;
      o[3] = s_wt;                       // depth0
      o[4] = s_w;                        // acc0
      o[5] = s_w * o0x + s_wt0 * d0x;    // pts0
      o[6] = s_w * o0y + s_wt0 * d0y;
      o[7] = s_w * o0z + s_wt0 * d0z;
    }
  }

  // ---- piecewise-constant PDF -> CDF (62 weights = w[1..62]) ----
  const float wnext = __shfl_down(w, 1);
  const float pw = (lane < NC-2) ? wnext : 0.f;
  const float ws_sum = wave_sum(pw);
  const float pad = fmaxf(1e-5f - ws_sum, 0.f);
  const float wsp = ws_sum + pad;
  const float pdf = (lane < NC-2) ? (pw + pad * (1.f/62.f)) / wsp : 0.f;
  float ip  = wave_incl_scan(pdf, lane);
  ip = wave_incl_max_scan(ip, lane);       // exact monotone
  if (lane < 61)  sCdf[lane+1] = fminf(ip, 1.f);
  if (lane == 61) sCdf[0]  = 0.f;
  if (lane == 62) sCdf[62] = 1.f;
  __builtin_amdgcn_wave_barrier();         // order LDS writes before reads (same wave)

  // ---- inverse-CDF: 128 samples, 2 per lane ----
  const float ustep = (1.0f - 1.1920929e-07f) / 127.0f;
#pragma unroll
  for (int r = 0; r < 2; ++r) {
    const int k = lane + 64*r;
    const float u = k * ustep;
    int lo = 0, hi = 61;                   // largest J with cdf[J] <= u
    while (lo < hi) {
      const int mid = (lo + hi + 1) >> 1;
      if (sCdf[mid] <= u) lo = mid; else hi = mid - 1;
    }
    const int J = lo;
    const float cg0 = sCdf[J],  cg1 = sCdf[J+1];
    const float bg0 = sBins[J], bg1 = sBins[J+1];
    const float denom = cg1 - cg0;
    const float num   = u - cg0;
    float tt;
    if (denom > 0.f) tt = fminf(fmaxf(num / denom, 0.f), 1.f);
    else             tt = (num > 0.f) ? 1.f : 0.f;
    sZs[k] = fmaf(tt, bg1 - bg0, bg0);
  }
  __builtin_amdgcn_wave_barrier();

  // ---- stable rank merge of sorted t (64) and z (128) into zdst (192) ----
  {
    int l = 0, r = NF;                     // count z < tv
    while (l < r) { const int m = (l + r) >> 1; if (sZs[m] < tv) l = m + 1; else r = m; }
    zdst[lane + l] = tv;
  }
#pragma unroll
  for (int r2 = 0; r2 < 2; ++r2) {
    const int k = lane + 64*r2;
    const float z = sZs[k];
    int l = 0, r = NC;                     // count t <= z
    while (l < r) { const int m = (l + r) >> 1; if (sT[m] <= z) l = m + 1; else r = m; }
    zdst[k + l] = z;
  }
  __builtin_amdgcn_wave_barrier();
}

// ---------------- Fused kernel: 4 waves = 4 rays per block, no global scratch
// __launch_bounds__(256,3): cap VGPR ~168 so the allocator can't balloon to
// 256 (R6: 2 waves/SIMD, latency-bound).
__global__ __launch_bounds__(256, 3) void nerf_fused_kernel(
    const float* __restrict__ origins, const float* __restrict__ dirs,
    const float* __restrict__ nearp, const float* __restrict__ farp,
    const float* __restrict__ bkgd,
    const float* __restrict__ w1c, const float* __restrict__ b1c,
    const float* __restrict__ w2c, const float* __restrict__ b2c,
    const float* __restrict__ wrc, const float* __restrict__ brc,
    const float* __restrict__ wdc, const float* __restrict__ bdc,
    const float* __restrict__ w1f, const float* __restrict__ b1f,
    const float* __restrict__ w2f, const float* __restrict__ b2f_,
    const float* __restrict__ wrf, const float* __restrict__ brf,
    const float* __restrict__ wdf, const float* __restrict__ bdf,
    float* __restrict__ out)
{
  __shared__ WLds sWc, sWf;
  __shared__ float sT[4][NC];
  __shared__ float sBins[4][NC];
  __shared__ float sCdf[4][NC];
  __shared__ float sZs[4][NF];
  __shared__ float sZv[4][NZ];
  __shared__ float sZv0[NZ];     // ray 0's fine z row (samples_f[0] quirk)

  const int tid  = threadIdx.x;
  const int wv   = tid >> 6;
  const int lane = tid & 63;
  const int ray  = blockIdx.x * 4 + wv;

  load_weights_lds(tid, w1c, b1c, b2c, wrc, wdc, sWc);
  load_weights_lds(tid, w1f, b1f, b2f_, wrf, wdf, sWf);
  __syncthreads();

  const float cb0 = brc[0], cb1 = brc[1], cb2 = brc[2], cbd = bdc[0];
  const float fb0 = brf[0], fb1 = brf[1], fb2 = brf[2], fbd = bdf[0];

  // own coarse pass -> own z row + coarse outputs
  coarse_pass(ray, lane, origins, dirs, nearp, farp, bkgd,
              sWc, w2c, cb0, cb1, cb2, cbd,
              sT[wv], sBins[wv], sCdf[wv], sZs[wv], sZv[wv], true, out);

  // wave 0 recomputes ray 0's z row for this block (deterministic, bit-identical)
  if (wv == 0) {
    coarse_pass(0, lane, origins, dirs, nearp, farp, bkgd,
                sWc, w2c, cb0, cb1, cb2, cbd,
                sT[0], sBins[0], sCdf[0], sZs[0], sZv0, false, out);
  }

  // ---- fine pass: 3 samples per lane ----
  const float ox = origins[ray*3+0], oy = origins[ray*3+1], oz = origins[ray*3+2];
  const float dx = dirs[ray*3+0],    dy = dirs[ray*3+1],    dz = dirs[ray*3+2];
  const float dnorm = sqrtf(dx*dx + dy*dy + dz*dz);

  float zc[3], zn[3];
#pragma unroll
  for (int s = 0; s < 3; ++s) {
    const int i = lane + 64*s;
    zc[s] = sZv[wv][i];
    zn[s] = (i < NZ-1) ? sZv[wv][i+1] : 0.f;
  }

  float rr0[3], rr1[3], rr2[3], dens[3];
#pragma unroll
  for (int s = 0; s < 3; ++s) {
    mlp_eval(ox + zc[s]*dx, oy + zc[s]*dy, oz + zc[s]*dz, sWf, w2f,
             fb0, fb1, fb2, fbd, rr0[s], rr1[s], rr2[s], dens[s]);
  }

  float dd[3];
#pragma unroll
  for (int s = 0; s < 3; ++s) {
    const int i = lane + 64*s;
    const float td = (i == NZ-1) ? 1e10f : fmaxf(zn[s] - zc[s], 0.f);
    dd[s] = fminf(dens[s] * (td * dnorm), 1e4f);
  }

  float excl[3];
  float offset = 0.f;
#pragma unroll
  for (int s = 0; s < 3; ++s) {
    const float incl = wave_incl_scan(dd[s], lane);
    excl[s] = offset + incl - dd[s];
    offset += __shfl(incl, 63);
  }

  __syncthreads();   // sZv0 ready (wave 0 wrote it above)

  float aw = 0.f, awz = 0.f, ac0 = 0.f, ac1 = 0.f, ac2 = 0.f, awz0 = 0.f;
#pragma unroll
  for (int s = 0; s < 3; ++s) {
    const int i = lane + 64*s;
    const float wgt = (1.f - expf(-dd[s])) * expf(-excl[s]);
    aw   += wgt;
    awz  += wgt * zc[s];
    ac0  += wgt * rr0[s];
    ac1  += wgt * rr1[s];
    ac2  += wgt * rr2[s];
    awz0 += wgt * sZv0[i];
  }
  aw  = wave_sum(aw);  awz = wave_sum(awz); ac0 = wave_sum(ac0);
  ac1 = wave_sum(ac1); ac2 = wave_sum(ac2); awz0 = wave_sum(awz0);

  if (lane == 0) {
    const float bk0 = bkgd[0], bk1 = bkgd[1], bk2 = bkgd[2];
    const float o0x = origins[0], o0y = origins[1], o0z = origins[2];
    const float d0x = dirs[0],    d0y = dirs[1],    d0z = dirs[2];
    const float oma = 1.f - aw;
    float* o = out + (size_t)ray * 16 + 8;
    o[0] = ac0 + bk0 * oma;
    o[1] = ac1 + bk1 * oma;
    o[2] = ac2 + bk2 * oma;
    o[3] = awz;                        // depth1
    o[4] = aw;                         // acc1
    o[5] = aw * o0x + awz0 * d0x;      // pts1
    o[6] = aw * o0y + awz0 * d0y;
    o[7] = aw * o0z + awz0 * d0z;
  }
}

extern "C" void kernel_launch(void* const* d_in, const int* in_sizes, int n_in,
                              void* d_out, int out_size, void* d_ws, size_t ws_size,
                              hipStream_t stream) {
  const float* origins = (const float*)d_in[0];
  const float* dirs    = (const float*)d_in[1];
  const float* nearp   = (const float*)d_in[2];
  const float* farp    = (const float*)d_in[3];
  const float* bkgd    = (const float*)d_in[4];
  const float* w1c  = (const float*)d_in[5];
  const float* b1c  = (const float*)d_in[6];
  const float* w2c  = (const float*)d_in[7];
  const float* b2c  = (const float*)d_in[8];
  const float* wrc  = (const float*)d_in[9];
  const float* brc  = (const float*)d_in[10];
  const float* wdc  = (const float*)d_in[11];
  const float* bdc  = (const float*)d_in[12];
  const float* w1f  = (const float*)d_in[13];
  const float* b1f  = (const float*)d_in[14];
  const float* w2f  = (const float*)d_in[15];
  const float* b2f_ = (const float*)d_in[16];
  const float* wrf  = (const float*)d_in[17];
  const float* brf  = (const float*)d_in[18];
  const float* wdf  = (const float*)d_in[19];
  const float* bdf  = (const float*)d_in[20];

  nerf_fused_kernel<<<NRAYS/4, 256, 0, stream>>>(
      origins, dirs, nearp, farp, bkgd,
      w1c, b1c, w2c, b2c, wrc, brc, wdc, bdc,
      w1f, b1f, w2f, b2f_, wrf, brf, wdf, bdf,
      (float*)d_out);
}

// Round 9
// 620.644 us; speedup vs baseline: 6.4932x; 6.4932x over previous
//
#include <hip/hip_runtime.h>
#include <math.h>

#define NRAYS 16384
#define NC    64
#define NF    128
#define NZ    192   // NC + NF
#define H     64
#define TPAD  65     // padded row stride (dwords) of the h2 transpose tile

typedef __attribute__((ext_vector_type(8))) short bf16x8;  // 8 bf16 (4 VGPRs)
typedef __attribute__((ext_vector_type(4))) float f32x4;   // MFMA C/D

__device__ __forceinline__ float wave_incl_scan(float v, int lane) {
#pragma unroll
  for (int off = 1; off < 64; off <<= 1) {
    float n = __shfl_up(v, off);
    v = (lane >= off) ? v + n : v;
  }
  return v;
}

__device__ __forceinline__ float wave_incl_max_scan(float v, int lane) {
#pragma unroll
  for (int off = 1; off < 64; off <<= 1) {
    float n = __shfl_up(v, off);
    v = (lane >= off) ? fmaxf(v, n) : v;
  }
  return v;
}

__device__ __forceinline__ float wave_sum(float v) {
#pragma unroll
  for (int off = 32; off > 0; off >>= 1) v += __shfl_xor(v, off);
  return v;
}

// fp32 -> bf16 hi + bf16 lo (truncation split; hi+lo captures ~16 mantissa
// bits; 3-term MFMA (hi*hi + lo*hi + hi*lo) has rel err ~3*2^-16).
__device__ __forceinline__ void split_bf16(float f, short& hi, short& lo) {
  unsigned u = __float_as_uint(f);
  hi = (short)(u >> 16);
  float rem = f - __uint_as_float(u & 0xFFFF0000u);   // exact
  lo = (short)(__float_as_uint(rem) >> 16);
}

__device__ __forceinline__ float sigmoidf(float x) {
  return 1.f / (1.f + expf(-x));
}

// Layer-1 weights in LDS (broadcast float4 reads).
struct __align__(16) WLds {
  float W1b[H][4];   // {w1[0][k], w1[1][k], w1[2][k], b1[k]}
};

__device__ __forceinline__ void load_w1_lds(
    int tid, const float* __restrict__ w1, const float* __restrict__ b1,
    WLds& W)
{
  // UNSIGNED guard: R8 called this with tid-64 (negative for tid<64); the
  // signed `tid < H` check passed and negative LDS indexing overwrote the
  // *previous* LDS struct (sWc) with OOB global garbage -> absmax 6.0.
  if ((unsigned)tid < (unsigned)H) {
    int k = tid;
    W.W1b[k][0] = w1[0*H + k];
    W.W1b[k][1] = w1[1*H + k];
    W.W1b[k][2] = w1[2*H + k];
    W.W1b[k][3] = b1[k];
  }
}

// Per-wave register-resident MFMA weight fragments for one MLP.
// 16x16x32 bf16 layouts (HW-verified, guide §3):
//   A[m][k]: m = lane&15, k = (lane>>4)*8 + j   (j = 0..7)
//   B[k][n]: n = lane&15, k = (lane>>4)*8 + j
//   C/D[m][n]: n = lane&15, m = (lane>>4)*4 + reg
struct MfmaW {
  bf16x8 Bhi[2][4], Blo[2][4];  // w2 [kt][jt]  (K tile 32, N tile 16)
  bf16x8 Hhi[2],    Hlo[2];     // head (64 x 16-padded: c0..2=wr, c3=wd, rest 0)
  f32x4  c2init;                // head bias by col
  float  b2v[4];                // b2[jt*16 + n16] per jt
};

__device__ __forceinline__ void load_mfma_weights(
    int lane,
    const float* __restrict__ w2, const float* __restrict__ b2,
    const float* __restrict__ wr, const float* __restrict__ br,
    const float* __restrict__ wd, const float* __restrict__ bd,
    MfmaW& M)
{
  const int quad = lane >> 4, n16 = lane & 15;
#pragma unroll
  for (int kt = 0; kt < 2; ++kt) {
#pragma unroll
    for (int jt = 0; jt < 4; ++jt) {
#pragma unroll
      for (int j = 0; j < 8; ++j) {
        const int k = kt*32 + quad*8 + j;
        short hi, lo;
        split_bf16(w2[k*H + jt*16 + n16], hi, lo);
        M.Bhi[kt][jt][j] = hi; M.Blo[kt][jt][j] = lo;
      }
    }
  }
#pragma unroll
  for (int kt = 0; kt < 2; ++kt) {
#pragma unroll
    for (int j = 0; j < 8; ++j) {
      const int k = kt*32 + quad*8 + j;
      const float v = (n16 < 3) ? wr[k*3 + n16] : ((n16 == 3) ? wd[k] : 0.f);
      short hi, lo;
      split_bf16(v, hi, lo);
      M.Hhi[kt][j] = hi; M.Hlo[kt][j] = lo;
    }
  }
  const float ci = (n16 == 0) ? br[0] : (n16 == 1) ? br[1]
                 : (n16 == 2) ? br[2] : (n16 == 3) ? bd[0] : 0.f;
  M.c2init = (f32x4){ci, ci, ci, ci};
#pragma unroll
  for (int jt = 0; jt < 4; ++jt) M.b2v[jt] = b2[jt*16 + n16];
}

// One 64-sample MLP batch for one ray (one wave). zsrc: 64 z-values in LDS.
// Writes per-sample head logits to R[m*4 + c] (c: 0..2 rgb-logit, 3 density).
// T: per-wave LDS transpose tile (16 x TPAD dwords). Uses MFMA for layer2+head.
__device__ __forceinline__ void mlp_mfma_batch(
    int lane, float ox, float oy, float oz, float dx, float dy, float dz,
    const float* __restrict__ zsrc, const WLds& W, const MfmaW& M,
    unsigned* __restrict__ T, float* __restrict__ R)
{
  const int quad = lane >> 4, n16 = lane & 15;
  for (int mt = 0; mt < 4; ++mt) {
    // ---- layer 1 directly in A-fragment layout; layer 2 via MFMA ----
    const float z  = zsrc[mt*16 + n16];
    const float x0 = fmaf(z, dx, ox);
    const float x1 = fmaf(z, dy, oy);
    const float x2 = fmaf(z, dz, oz);
    f32x4 C[4];
#pragma unroll
    for (int jt = 0; jt < 4; ++jt)
      C[jt] = (f32x4){M.b2v[jt], M.b2v[jt], M.b2v[jt], M.b2v[jt]};
#pragma unroll
    for (int kt = 0; kt < 2; ++kt) {
      bf16x8 ahi, alo;
#pragma unroll
      for (int j = 0; j < 8; ++j) {
        const int k = kt*32 + quad*8 + j;
        const float4 wv = *(const float4*)(&W.W1b[k][0]);
        const float h =
            fmaxf(fmaf(x0, wv.x, fmaf(x1, wv.y, fmaf(x2, wv.z, wv.w))), 0.f);
        short hi, lo; split_bf16(h, hi, lo);
        ahi[j] = hi; alo[j] = lo;
      }
#pragma unroll
      for (int jt = 0; jt < 4; ++jt) {
        C[jt] = __builtin_amdgcn_mfma_f32_16x16x32_bf16(ahi, M.Bhi[kt][jt], C[jt], 0, 0, 0);
        C[jt] = __builtin_amdgcn_mfma_f32_16x16x32_bf16(alo, M.Bhi[kt][jt], C[jt], 0, 0, 0);
        C[jt] = __builtin_amdgcn_mfma_f32_16x16x32_bf16(ahi, M.Blo[kt][jt], C[jt], 0, 0, 0);
      }
    }
    // ---- relu(h2) -> split-bf16 packed -> LDS tile (C-layout -> A-layout) ----
#pragma unroll
    for (int jt = 0; jt < 4; ++jt) {
#pragma unroll
      for (int r = 0; r < 4; ++r) {
        const float h2 = fmaxf(C[jt][r], 0.f);
        short hi, lo; split_bf16(h2, hi, lo);
        T[(quad*4 + r)*TPAD + jt*16 + n16] =
            ((unsigned)(unsigned short)hi << 16) | (unsigned)(unsigned short)lo;
      }
    }
    __builtin_amdgcn_wave_barrier();
    // ---- head: D2[m][c] = relu(h2)[m][:] @ Whead ----
    f32x4 C2 = M.c2init;
#pragma unroll
    for (int kt2 = 0; kt2 < 2; ++kt2) {
      bf16x8 a2h, a2l;
#pragma unroll
      for (int j = 0; j < 8; ++j) {
        const unsigned v = T[n16*TPAD + kt2*32 + quad*8 + j];
        a2h[j] = (short)(v >> 16);
        a2l[j] = (short)(v & 0xFFFFu);
      }
      C2 = __builtin_amdgcn_mfma_f32_16x16x32_bf16(a2h, M.Hhi[kt2], C2, 0, 0, 0);
      C2 = __builtin_amdgcn_mfma_f32_16x16x32_bf16(a2l, M.Hhi[kt2], C2, 0, 0, 0);
      C2 = __builtin_amdgcn_mfma_f32_16x16x32_bf16(a2h, M.Hlo[kt2], C2, 0, 0, 0);
    }
    __builtin_amdgcn_wave_barrier();   // T reused next mt
    if (n16 < 4) {
#pragma unroll
      for (int r = 0; r < 4; ++r)
        R[(mt*16 + quad*4 + r)*4 + n16] = C2[r];
    }
  }
  __builtin_amdgcn_wave_barrier();     // R complete before readback
}

// Coarse pass for one ray, executed by ONE wave (wave-private LDS scratch).
__device__ __forceinline__ void coarse_pass(
    int ray, int lane,
    const float* __restrict__ origins, const float* __restrict__ dirs,
    const float* __restrict__ nearp, const float* __restrict__ farp,
    const float* __restrict__ bkgd,
    const WLds& W, const MfmaW& M,
    unsigned* __restrict__ T, float* __restrict__ R,
    float* __restrict__ sT, float* __restrict__ sBins,
    float* __restrict__ sCdf, float* __restrict__ sZs,
    float* __restrict__ zdst, bool emit, float* __restrict__ out)
{
  const float nearv = nearp[ray];
  const float farv  = farp[ray];
  const float ox = origins[ray*3+0], oy = origins[ray*3+1], oz = origins[ray*3+2];
  const float dx = dirs[ray*3+0],    dy = dirs[ray*3+1],    dz = dirs[ray*3+2];

  const float u_i  = (float)lane / 63.0f;
  const float u_n  = (float)(lane + 1) / 63.0f;
  const float tv    = nearv * (1.f - u_i) + farv * u_i;
  const float tnext = nearv * (1.f - u_n) + farv * u_n;

  sT[lane] = tv;
  if (lane < NC-1) sBins[lane] = 0.5f * (tv + tnext);
  zdst[lane] = 0.f; zdst[lane+64] = 0.f; zdst[lane+128] = 0.f;
  __builtin_amdgcn_wave_barrier();     // sT ready for the batch

  mlp_mfma_batch(lane, ox, oy, oz, dx, dy, dz, sT, W, M, T, R);
  const float4 rr = *(const float4*)(&R[lane*4]);
  const float rgb0 = sigmoidf(rr.x), rgb1 = sigmoidf(rr.y), rgb2 = sigmoidf(rr.z);
  const float dens = fmaxf(rr.w, 0.f);

  const float dnorm = sqrtf(dx*dx + dy*dy + dz*dz);
  const float tdist = (lane == NC-1) ? 1e10f : (tnext - tv);
  const float dd    = fminf(dens * (tdist * dnorm), 1e4f);
  const float incl  = wave_incl_scan(dd, lane);
  const float excl  = incl - dd;
  const float alpha = 1.f - expf(-dd);
  const float trans = expf(-excl);
  const float w     = alpha * trans;

  if (emit) {
    const float near0 = nearp[0], far0 = farp[0];
    const float t0v   = near0 * (1.f - u_i) + far0 * u_i;
    const float s_w   = wave_sum(w);
    const float s_wt  = wave_sum(w * tv);
    const float s_c0  = wave_sum(w * rgb0);
    const float s_c1  = wave_sum(w * rgb1);
    const float s_c2  = wave_sum(w * rgb2);
    const float s_wt0 = wave_sum(w * t0v);
    if (lane == 0) {
      const float bk0 = bkgd[0], bk1 = bkgd[1], bk2 = bkgd[2];
      const float o0x = origins[0], o0y = origins[1], o0z = origins[2];
      const float d0x = dirs[0],    d0y = dirs[1],    d0z = dirs[2];
      const float oma = 1.f - s_w;
      float* o = out + (size_t)ray * 16;
      o[0] = s_c0 + bk0 * oma;
      o[1] = s_c1 + bk1 * oma;
      o[2] = s_c2 + bk2 * oma;
      o[3] = s_wt;
      o[4] = s_w;
      o[5] = s_w * o0x + s_wt0 * d0x;
      o[6] = s_w * o0y + s_wt0 * d0y;
      o[7] = s_w * o0z + s_wt0 * d0z;
    }
  }

  // ---- PDF -> CDF (62 weights = w[1..62]) ----
  const float wnext = __shfl_down(w, 1);
  const float pw = (lane < NC-2) ? wnext : 0.f;
  const float ws_sum = wave_sum(pw);
  const float pad = fmaxf(1e-5f - ws_sum, 0.f);
  const float wsp = ws_sum + pad;
  const float pdf = (lane < NC-2) ? (pw + pad * (1.f/62.f)) / wsp : 0.f;
  float ip  = wave_incl_scan(pdf, lane);
  ip = wave_incl_max_scan(ip, lane);       // exact monotone
  if (lane < 61)  sCdf[lane+1] = fminf(ip, 1.f);
  if (lane == 61) sCdf[0]  = 0.f;
  if (lane == 62) sCdf[62] = 1.f;
  __builtin_amdgcn_wave_barrier();

  // ---- inverse-CDF: 128 samples, 2 per lane ----
  const float ustep = (1.0f - 1.1920929e-07f) / 127.0f;
#pragma unroll
  for (int r = 0; r < 2; ++r) {
    const int k = lane + 64*r;
    const float u = k * ustep;
    int lo = 0, hi = 61;
    while (lo < hi) {
      const int mid = (lo + hi + 1) >> 1;
      if (sCdf[mid] <= u) lo = mid; else hi = mid - 1;
    }
    const int J = lo;
    const float cg0 = sCdf[J],  cg1 = sCdf[J+1];
    const float bg0 = sBins[J], bg1 = sBins[J+1];
    const float denom = cg1 - cg0;
    const float num   = u - cg0;
    float tt;
    if (denom > 0.f) tt = fminf(fmaxf(num / denom, 0.f), 1.f);
    else             tt = (num > 0.f) ? 1.f : 0.f;
    sZs[k] = fmaf(tt, bg1 - bg0, bg0);
  }
  __builtin_amdgcn_wave_barrier();

  // ---- stable rank merge of sorted t (64) and z (128) into zdst (192) ----
  {
    int l = 0, r = NF;
    while (l < r) { const int m = (l + r) >> 1; if (sZs[m] < tv) l = m + 1; else r = m; }
    zdst[lane + l] = tv;
  }
#pragma unroll
  for (int r2 = 0; r2 < 2; ++r2) {
    const int k = lane + 64*r2;
    const float z = sZs[k];
    int l = 0, r = NC;
    while (l < r) { const int m = (l + r) >> 1; if (sT[m] <= z) l = m + 1; else r = m; }
    zdst[k + l] = z;
  }
  __builtin_amdgcn_wave_barrier();
}

// ---------------- Fused kernel: 4 waves = 4 rays per block, no global scratch
__global__ __launch_bounds__(256) void nerf_fused_kernel(
    const float* __restrict__ origins, const float* __restrict__ dirs,
    const float* __restrict__ nearp, const float* __restrict__ farp,
    const float* __restrict__ bkgd,
    const float* __restrict__ w1c, const float* __restrict__ b1c,
    const float* __restrict__ w2c, const float* __restrict__ b2c,
    const float* __restrict__ wrc, const float* __restrict__ brc,
    const float* __restrict__ wdc, const float* __restrict__ bdc,
    const float* __restrict__ w1f, const float* __restrict__ b1f,
    const float* __restrict__ w2f, const float* __restrict__ b2f_,
    const float* __restrict__ wrf, const float* __restrict__ brf,
    const float* __restrict__ wdf, const float* __restrict__ bdf,
    float* __restrict__ out)
{
  __shared__ WLds sWc, sWf;
  __shared__ float sT[4][NC];
  __shared__ float sBins[4][NC];
  __shared__ float sCdf[4][NC];
  __shared__ float sZs[4][NF];
  __shared__ float sZv[4][NZ];
  __shared__ float sZv0[NZ];                // ray 0's fine z row (quirk)
  __shared__ unsigned sTr[4][16*TPAD];      // per-wave h2 transpose tile
  __shared__ float sR[4][64*4];             // per-wave head logits

  const int tid  = threadIdx.x;
  const int wv   = tid >> 6;
  const int lane = tid & 63;
  const int ray  = blockIdx.x * 4 + wv;

  load_w1_lds(tid, w1c, b1c, sWc);
  load_w1_lds(tid - 64, w1f, b1f, sWf);     // threads 64..127 (unsigned guard)
  __syncthreads();

  unsigned* T = sTr[wv];
  float*    R = sR[wv];

  // ---- coarse MLP weight frags (registers), coarse pass(es) ----
  {
    MfmaW Mc;
    load_mfma_weights(lane, w2c, b2c, wrc, brc, wdc, bdc, Mc);

    coarse_pass(ray, lane, origins, dirs, nearp, farp, bkgd,
                sWc, Mc, T, R,
                sT[wv], sBins[wv], sCdf[wv], sZs[wv], sZv[wv], true, out);

    if (wv == 0) {
      coarse_pass(0, lane, origins, dirs, nearp, farp, bkgd,
                  sWc, Mc, T, R,
                  sT[0], sBins[0], sCdf[0], sZs[0], sZv0, false, out);
    }
  }

  // ---- fine pass: 3 batches of 64 samples ----
  MfmaW Mf;
  load_mfma_weights(lane, w2f, b2f_, wrf, brf, wdf, bdf, Mf);

  const float ox = origins[ray*3+0], oy = origins[ray*3+1], oz = origins[ray*3+2];
  const float dx = dirs[ray*3+0],    dy = dirs[ray*3+1],    dz = dirs[ray*3+2];
  const float dnorm = sqrtf(dx*dx + dy*dy + dz*dz);

  float zc[3], zn[3];
#pragma unroll
  for (int s = 0; s < 3; ++s) {
    const int i = lane + 64*s;
    zc[s] = sZv[wv][i];
    zn[s] = (i < NZ-1) ? sZv[wv][i+1] : 0.f;
  }

  float rr0[3], rr1[3], rr2[3], dens[3];
#pragma unroll
  for (int s = 0; s < 3; ++s) {
    mlp_mfma_batch(lane, ox, oy, oz, dx, dy, dz, &sZv[wv][64*s], sWf, Mf, T, R);
    const float4 rr = *(const float4*)(&R[lane*4]);
    rr0[s] = sigmoidf(rr.x);
    rr1[s] = sigmoidf(rr.y);
    rr2[s] = sigmoidf(rr.z);
    dens[s] = fmaxf(rr.w, 0.f);
  }

  float dd[3];
#pragma unroll
  for (int s = 0; s < 3; ++s) {
    const int i = lane + 64*s;
    const float td = (i == NZ-1) ? 1e10f : fmaxf(zn[s] - zc[s], 0.f);
    dd[s] = fminf(dens[s] * (td * dnorm), 1e4f);
  }

  float excl[3];
  float offset = 0.f;
#pragma unroll
  for (int s = 0; s < 3; ++s) {
    const float incl = wave_incl_scan(dd[s], lane);
    excl[s] = offset + incl - dd[s];
    offset += __shfl(incl, 63);
  }

  __syncthreads();   // sZv0 ready (wave 0 wrote it in its second coarse_pass)

  float aw = 0.f, awz = 0.f, ac0 = 0.f, ac1 = 0.f, ac2 = 0.f, awz0 = 0.f;
#pragma unroll
  for (int s = 0; s < 3; ++s) {
    const int i = lane + 64*s;
    const float wgt = (1.f - expf(-dd[s])) * expf(-excl[s]);
    aw   += wgt;
    awz  += wgt * zc[s];
    ac0  += wgt * rr0[s];
    ac1  += wgt * rr1[s];
    ac2  += wgt * rr2[s];
    awz0 += wgt * sZv0[i];
  }
  aw  = wave_sum(aw);  awz = wave_sum(awz); ac0 = wave_sum(ac0);
  ac1 = wave_sum(ac1); ac2 = wave_sum(ac2); awz0 = wave_sum(awz0);

  if (lane == 0) {
    const float bk0 = bkgd[0], bk1 = bkgd[1], bk2 = bkgd[2];
    const float o0x = origins[0], o0y = origins[1], o0z = origins[2];
    const float d0x = dirs[0],    d0y = dirs[1],    d0z = dirs[2];
    const float oma = 1.f - aw;
    float* o = out + (size_t)ray * 16 + 8;
    o[0] = ac0 + bk0 * oma;
    o[1] = ac1 + bk1 * oma;
    o[2] = ac2 + bk2 * oma;
    o[3] = awz;
    o[4] = aw;
    o[5] = aw * o0x + awz0 * d0x;
    o[6] = aw * o0y + awz0 * d0y;
    o[7] = aw * o0z + awz0 * d0z;
  }
}

extern "C" void kernel_launch(void* const* d_in, const int* in_sizes, int n_in,
                              void* d_out, int out_size, void* d_ws, size_t ws_size,
                              hipStream_t stream) {
  const float* origins = (const float*)d_in[0];
  const float* dirs    = (const float*)d_in[1];
  const float* nearp   = (const float*)d_in[2];
  const float* farp    = (const float*)d_in[3];
  const float* bkgd    = (const float*)d_in[4];
  const float* w1c  = (const float*)d_in[5];
  const float* b1c  = (const float*)d_in[6];
  const float* w2c  = (const float*)d_in[7];
  const float* b2c  = (const float*)d_in[8];
  const float* wrc  = (const float*)d_in[9];
  const float* brc  = (const float*)d_in[10];
  const float* wdc  = (const float*)d_in[11];
  const float* bdc  = (const float*)d_in[12];
  const float* w1f  = (const float*)d_in[13];
  const float* b1f  = (const float*)d_in[14];
  const float* w2f  = (const float*)d_in[15];
  const float* b2f_ = (const float*)d_in[16];
  const float* wrf  = (const float*)d_in[17];
  const float* brf  = (const float*)d_in[18];
  const float* wdf  = (const float*)d_in[19];
  const float* bdf  = (const float*)d_in[20];

  nerf_fused_kernel<<<NRAYS/4, 256, 0, stream>>>(
      origins, dirs, nearp, farp, bkgd,
      w1c, b1c, w2c, b2c, wrc, brc, wdc, bdc,
      w1f, b1f, w2f, b2f_, wrf, brf, wdf, bdf,
      (float*)d_out);
}

// Round 10
// 573.488 us; speedup vs baseline: 7.0271x; 1.0822x over previous
//
#include <hip/hip_runtime.h>
#include <math.h>

#define NRAYS 16384
#define NC    64
#define NF    128
#define NZ    192   // NC + NF
#define H     64

typedef __attribute__((ext_vector_type(8))) short bf16x8;  // 8 bf16 (4 VGPRs)
typedef __attribute__((ext_vector_type(4))) float f32x4;   // MFMA C/D

__device__ __forceinline__ float wave_incl_scan(float v, int lane) {
#pragma unroll
  for (int off = 1; off < 64; off <<= 1) {
    float n = __shfl_up(v, off);
    v = (lane >= off) ? v + n : v;
  }
  return v;
}

__device__ __forceinline__ float wave_incl_max_scan(float v, int lane) {
#pragma unroll
  for (int off = 1; off < 64; off <<= 1) {
    float n = __shfl_up(v, off);
    v = (lane >= off) ? fmaxf(v, n) : v;
  }
  return v;
}

__device__ __forceinline__ float wave_sum(float v) {
#pragma unroll
  for (int off = 32; off > 0; off >>= 1) v += __shfl_xor(v, off);
  return v;
}

// fp32 -> bf16 hi + bf16 lo (truncation split; 3-term MFMA
// (hi*hi + lo*hi + hi*lo) has rel err ~2^-15).
__device__ __forceinline__ void split_bf16(float f, short& hi, short& lo) {
  unsigned u = __float_as_uint(f);
  hi = (short)(u >> 16);
  float rem = f - __uint_as_float(u & 0xFFFF0000u);   // exact
  lo = (short)(__float_as_uint(rem) >> 16);
}

__device__ __forceinline__ float sigmoidf(float x) {
  return 1.f / (1.f + expf(-x));
}

// Layer-1 weights in LDS (broadcast float4 reads).
struct __align__(16) WLds {
  float W1b[H][4];   // {w1[0][k], w1[1][k], w1[2][k], b1[k]}
};

__device__ __forceinline__ void load_w1_lds(
    int tid, const float* __restrict__ w1, const float* __restrict__ b1,
    WLds& W)
{
  // UNSIGNED guard (R8 bug: negative tid passed the signed check and
  // corrupted the preceding LDS struct).
  if ((unsigned)tid < (unsigned)H) {
    int k = tid;
    W.W1b[k][0] = w1[0*H + k];
    W.W1b[k][1] = w1[1*H + k];
    W.W1b[k][2] = w1[2*H + k];
    W.W1b[k][3] = b1[k];
  }
}

// Per-wave register-resident weights for one MLP.
// 16x16x32 bf16 layouts (HW-verified, guide §3):
//   A[m][k]: m = lane&15, k = (lane>>4)*8 + j   (j = 0..7)
//   B[k][n]: n = lane&15, k = (lane>>4)*8 + j
//   C/D[m][n]: n = lane&15, m = (lane>>4)*4 + reg
// Head (64x4) is done in fp32 VALU (R10): per-lane wh[jt][c] = whead[16jt+n16][c].
struct MfmaW {
  bf16x8 Bhi[2][4], Blo[2][4];  // w2 [kt][jt]  (K tile 32, N tile 16)
  float  whv[4][4];             // head weights [jt][c]
  float  hbown;                 // head bias for this lane's c = n16&3
  float  b2v[4];                // b2[jt*16 + n16] per jt
};

__device__ __forceinline__ void load_mfma_weights(
    int lane,
    const float* __restrict__ w2, const float* __restrict__ b2,
    const float* __restrict__ wr, const float* __restrict__ br,
    const float* __restrict__ wd, const float* __restrict__ bd,
    MfmaW& M)
{
  const int quad = lane >> 4, n16 = lane & 15;
#pragma unroll
  for (int kt = 0; kt < 2; ++kt) {
#pragma unroll
    for (int jt = 0; jt < 4; ++jt) {
#pragma unroll
      for (int j = 0; j < 8; ++j) {
        const int k = kt*32 + quad*8 + j;
        short hi, lo;
        split_bf16(w2[k*H + jt*16 + n16], hi, lo);
        M.Bhi[kt][jt][j] = hi; M.Blo[kt][jt][j] = lo;
      }
    }
  }
#pragma unroll
  for (int jt = 0; jt < 4; ++jt) {
    const int k = jt*16 + n16;
    M.whv[jt][0] = wr[k*3 + 0];
    M.whv[jt][1] = wr[k*3 + 1];
    M.whv[jt][2] = wr[k*3 + 2];
    M.whv[jt][3] = wd[k];
  }
  const int c = n16 & 3;
  M.hbown = (c == 0) ? br[0] : (c == 1) ? br[1] : (c == 2) ? br[2] : bd[0];
#pragma unroll
  for (int jt = 0; jt < 4; ++jt) M.b2v[jt] = b2[jt*16 + n16];
}

// One 64-sample MLP batch for one ray (one wave). zsrc: 64 z-values in LDS.
// Layer 2 via split-bf16 MFMA; head via in-lane fp32 products + halving
// butterfly reduction (R10: replaces the LDS-transpose + head-MFMA path,
// which cost a 4-way-conflicted LDS round trip per mt tile).
// Output: R[sample*4 + c] (c: 0..2 rgb-logit, 3 density-logit), bias included.
__device__ __forceinline__ void mlp_mfma_batch(
    int lane, float ox, float oy, float oz, float dx, float dy, float dz,
    const float* __restrict__ zsrc, const WLds& W, const MfmaW& M,
    float* __restrict__ R)
{
  const int quad = lane >> 4, n16 = lane & 15;
#pragma unroll 1   // rolled: prevents register blow-up (R5/R6 lesson)
  for (int mt = 0; mt < 4; ++mt) {
    // ---- layer 1 directly in A-fragment layout; layer 2 via MFMA ----
    const float z  = zsrc[mt*16 + n16];
    const float x0 = fmaf(z, dx, ox);
    const float x1 = fmaf(z, dy, oy);
    const float x2 = fmaf(z, dz, oz);
    f32x4 C[4];
#pragma unroll
    for (int jt = 0; jt < 4; ++jt)
      C[jt] = (f32x4){M.b2v[jt], M.b2v[jt], M.b2v[jt], M.b2v[jt]};
#pragma unroll
    for (int kt = 0; kt < 2; ++kt) {
      bf16x8 ahi, alo;
#pragma unroll
      for (int j = 0; j < 8; ++j) {
        const int k = kt*32 + quad*8 + j;
        const float4 wv = *(const float4*)(&W.W1b[k][0]);
        const float h =
            fmaxf(fmaf(x0, wv.x, fmaf(x1, wv.y, fmaf(x2, wv.z, wv.w))), 0.f);
        short hi, lo; split_bf16(h, hi, lo);
        ahi[j] = hi; alo[j] = lo;
      }
#pragma unroll
      for (int jt = 0; jt < 4; ++jt) {
        C[jt] = __builtin_amdgcn_mfma_f32_16x16x32_bf16(ahi, M.Bhi[kt][jt], C[jt], 0, 0, 0);
        C[jt] = __builtin_amdgcn_mfma_f32_16x16x32_bf16(alo, M.Bhi[kt][jt], C[jt], 0, 0, 0);
        C[jt] = __builtin_amdgcn_mfma_f32_16x16x32_bf16(ahi, M.Blo[kt][jt], C[jt], 0, 0, 0);
      }
    }
    // ---- head in fp32: P[r*4+c] = sum_jt relu(C[jt][r]) * wh[16jt+n16][c] ----
    float P[16];
#pragma unroll
    for (int r = 0; r < 4; ++r) {
#pragma unroll
      for (int c = 0; c < 4; ++c) P[r*4 + c] = 0.f;
#pragma unroll
      for (int jt = 0; jt < 4; ++jt) {
        const float h2v = fmaxf(C[jt][r], 0.f);
#pragma unroll
        for (int c = 0; c < 4; ++c)
          P[r*4 + c] = fmaf(h2v, M.whv[jt][c], P[r*4 + c]);
      }
    }
    // ---- halving reduce across the 16 lanes of this quad-group:
    // after 4 stages lane n16 holds total for i = n16 -> (m=4q+(n16>>2), c=n16&3)
    const bool b0 = (n16 & 1), b1 = (n16 & 2), b2_ = (n16 & 4), b3 = (n16 & 8);
    float Q[8];
#pragma unroll
    for (int s = 0; s < 8; ++s) {
      const float give = b0 ? P[2*s] : P[2*s+1];
      const float keep = b0 ? P[2*s+1] : P[2*s];
      Q[s] = keep + __shfl_xor(give, 1);
    }
    float U[4];
#pragma unroll
    for (int t = 0; t < 4; ++t) {
      const float give = b1 ? Q[2*t] : Q[2*t+1];
      const float keep = b1 ? Q[2*t+1] : Q[2*t];
      U[t] = keep + __shfl_xor(give, 2);
    }
    float V[2];
#pragma unroll
    for (int u = 0; u < 2; ++u) {
      const float give = b2_ ? U[2*u] : U[2*u+1];
      const float keep = b2_ ? U[2*u+1] : U[2*u];
      V[u] = keep + __shfl_xor(give, 4);
    }
    {
      const float give = b3 ? V[0] : V[1];
      const float keep = b3 ? V[1] : V[0];
      const float total = keep + __shfl_xor(give, 8);
      // addr = (sample)*4 + c = mt*64 + lane  (perfectly coalesced)
      R[mt*64 + lane] = total + M.hbown;
    }
  }
  __builtin_amdgcn_wave_barrier();     // R complete before readback
}

// Coarse pass for one ray, executed by ONE wave (wave-private LDS scratch).
__device__ __forceinline__ void coarse_pass(
    int ray, int lane,
    const float* __restrict__ origins, const float* __restrict__ dirs,
    const float* __restrict__ nearp, const float* __restrict__ farp,
    const float* __restrict__ bkgd,
    const WLds& W, const MfmaW& M, float* __restrict__ R,
    float* __restrict__ sT, float* __restrict__ sBins,
    float* __restrict__ sCdf, float* __restrict__ sZs,
    float* __restrict__ zdst, bool emit, float* __restrict__ out)
{
  const float nearv = nearp[ray];
  const float farv  = farp[ray];
  const float ox = origins[ray*3+0], oy = origins[ray*3+1], oz = origins[ray*3+2];
  const float dx = dirs[ray*3+0],    dy = dirs[ray*3+1],    dz = dirs[ray*3+2];

  const float u_i  = (float)lane / 63.0f;
  const float u_n  = (float)(lane + 1) / 63.0f;
  const float tv    = nearv * (1.f - u_i) + farv * u_i;
  const float tnext = nearv * (1.f - u_n) + farv * u_n;

  sT[lane] = tv;
  if (lane < NC-1) sBins[lane] = 0.5f * (tv + tnext);
  zdst[lane] = 0.f; zdst[lane+64] = 0.f; zdst[lane+128] = 0.f;
  __builtin_amdgcn_wave_barrier();     // sT ready for the batch

  mlp_mfma_batch(lane, ox, oy, oz, dx, dy, dz, sT, W, M, R);
  const float4 rr = *(const float4*)(&R[lane*4]);
  const float rgb0 = sigmoidf(rr.x), rgb1 = sigmoidf(rr.y), rgb2 = sigmoidf(rr.z);
  const float dens = fmaxf(rr.w, 0.f);

  const float dnorm = sqrtf(dx*dx + dy*dy + dz*dz);
  const float tdist = (lane == NC-1) ? 1e10f : (tnext - tv);
  const float dd    = fminf(dens * (tdist * dnorm), 1e4f);
  const float incl  = wave_incl_scan(dd, lane);
  const float excl  = incl - dd;
  const float alpha = 1.f - expf(-dd);
  const float trans = expf(-excl);
  const float w     = alpha * trans;

  if (emit) {
    const float near0 = nearp[0], far0 = farp[0];
    const float t0v   = near0 * (1.f - u_i) + far0 * u_i;
    const float s_w   = wave_sum(w);
    const float s_wt  = wave_sum(w * tv);
    const float s_c0  = wave_sum(w * rgb0);
    const float s_c1  = wave_sum(w * rgb1);
    const float s_c2  = wave_sum(w * rgb2);
    const float s_wt0 = wave_sum(w * t0v);
    if (lane == 0) {
      const float bk0 = bkgd[0], bk1 = bkgd[1], bk2 = bkgd[2];
      const float o0x = origins[0], o0y = origins[1], o0z = origins[2];
      const float d0x = dirs[0],    d0y = dirs[1],    d0z = dirs[2];
      const float oma = 1.f - s_w;
      float* o = out + (size_t)ray * 16;
      o[0] = s_c0 + bk0 * oma;
      o[1] = s_c1 + bk1 * oma;
      o[2] = s_c2 + bk2 * oma;
      o[3] = s_wt;
      o[4] = s_w;
      o[5] = s_w * o0x + s_wt0 * d0x;
      o[6] = s_w * o0y + s_wt0 * d0y;
      o[7] = s_w * o0z + s_wt0 * d0z;
    }
  }

  // ---- PDF -> CDF (62 weights = w[1..62]) ----
  const float wnext = __shfl_down(w, 1);
  const float pw = (lane < NC-2) ? wnext : 0.f;
  const float ws_sum = wave_sum(pw);
  const float pad = fmaxf(1e-5f - ws_sum, 0.f);
  const float wsp = ws_sum + pad;
  const float pdf = (lane < NC-2) ? (pw + pad * (1.f/62.f)) / wsp : 0.f;
  float ip  = wave_incl_scan(pdf, lane);
  ip = wave_incl_max_scan(ip, lane);       // exact monotone
  if (lane < 61)  sCdf[lane+1] = fminf(ip, 1.f);
  if (lane == 61) sCdf[0]  = 0.f;
  if (lane == 62) sCdf[62] = 1.f;
  __builtin_amdgcn_wave_barrier();

  // ---- inverse-CDF: 128 samples, 2 per lane ----
  const float ustep = (1.0f - 1.1920929e-07f) / 127.0f;
#pragma unroll
  for (int r = 0; r < 2; ++r) {
    const int k = lane + 64*r;
    const float u = k * ustep;
    int lo = 0, hi = 61;
    while (lo < hi) {
      const int mid = (lo + hi + 1) >> 1;
      if (sCdf[mid] <= u) lo = mid; else hi = mid - 1;
    }
    const int J = lo;
    const float cg0 = sCdf[J],  cg1 = sCdf[J+1];
    const float bg0 = sBins[J], bg1 = sBins[J+1];
    const float denom = cg1 - cg0;
    const float num   = u - cg0;
    float tt;
    if (denom > 0.f) tt = fminf(fmaxf(num / denom, 0.f), 1.f);
    else             tt = (num > 0.f) ? 1.f : 0.f;
    sZs[k] = fmaf(tt, bg1 - bg0, bg0);
  }
  __builtin_amdgcn_wave_barrier();

  // ---- stable rank merge of sorted t (64) and z (128) into zdst (192) ----
  {
    int l = 0, r = NF;
    while (l < r) { const int m = (l + r) >> 1; if (sZs[m] < tv) l = m + 1; else r = m; }
    zdst[lane + l] = tv;
  }
#pragma unroll
  for (int r2 = 0; r2 < 2; ++r2) {
    const int k = lane + 64*r2;
    const float z = sZs[k];
    int l = 0, r = NC;
    while (l < r) { const int m = (l + r) >> 1; if (sT[m] <= z) l = m + 1; else r = m; }
    zdst[k + l] = z;
  }
  __builtin_amdgcn_wave_barrier();
}

// ---------------- Fused kernel: 4 waves = 4 rays per block, no global scratch
__global__ __launch_bounds__(256) void nerf_fused_kernel(
    const float* __restrict__ origins, const float* __restrict__ dirs,
    const float* __restrict__ nearp, const float* __restrict__ farp,
    const float* __restrict__ bkgd,
    const float* __restrict__ w1c, const float* __restrict__ b1c,
    const float* __restrict__ w2c, const float* __restrict__ b2c,
    const float* __restrict__ wrc, const float* __restrict__ brc,
    const float* __restrict__ wdc, const float* __restrict__ bdc,
    const float* __restrict__ w1f, const float* __restrict__ b1f,
    const float* __restrict__ w2f, const float* __restrict__ b2f_,
    const float* __restrict__ wrf, const float* __restrict__ brf,
    const float* __restrict__ wdf, const float* __restrict__ bdf,
    float* __restrict__ out)
{
  __shared__ WLds sWc, sWf;
  __shared__ float sT[4][NC];
  __shared__ float sBins[4][NC];
  __shared__ float sCdf[4][NC];
  __shared__ float sZs[4][NF];
  __shared__ float sZv[4][NZ];
  __shared__ float sZv0[NZ];                // ray 0's fine z row (quirk)
  __shared__ float sR[4][64*4];             // per-wave head logits

  const int tid  = threadIdx.x;
  const int wv   = tid >> 6;
  const int lane = tid & 63;
  const int ray  = blockIdx.x * 4 + wv;

  load_w1_lds(tid, w1c, b1c, sWc);
  load_w1_lds(tid - 64, w1f, b1f, sWf);     // threads 64..127 (unsigned guard)
  __syncthreads();

  float* R = sR[wv];

  // ---- coarse MLP weight frags (registers), coarse pass(es) ----
  {
    MfmaW Mc;
    load_mfma_weights(lane, w2c, b2c, wrc, brc, wdc, bdc, Mc);

    coarse_pass(ray, lane, origins, dirs, nearp, farp, bkgd,
                sWc, Mc, R,
                sT[wv], sBins[wv], sCdf[wv], sZs[wv], sZv[wv], true, out);

    if (wv == 0) {
      coarse_pass(0, lane, origins, dirs, nearp, farp, bkgd,
                  sWc, Mc, R,
                  sT[0], sBins[0], sCdf[0], sZs[0], sZv0, false, out);
    }
  }

  // ---- fine pass: 3 batches of 64 samples ----
  MfmaW Mf;
  load_mfma_weights(lane, w2f, b2f_, wrf, brf, wdf, bdf, Mf);

  const float ox = origins[ray*3+0], oy = origins[ray*3+1], oz = origins[ray*3+2];
  const float dx = dirs[ray*3+0],    dy = dirs[ray*3+1],    dz = dirs[ray*3+2];
  const float dnorm = sqrtf(dx*dx + dy*dy + dz*dz);

  float zc[3], zn[3];
#pragma unroll
  for (int s = 0; s < 3; ++s) {
    const int i = lane + 64*s;
    zc[s] = sZv[wv][i];
    zn[s] = (i < NZ-1) ? sZv[wv][i+1] : 0.f;
  }

  float rr0[3], rr1[3], rr2[3], dens[3];
#pragma unroll
  for (int s = 0; s < 3; ++s) {
    mlp_mfma_batch(lane, ox, oy, oz, dx, dy, dz, &sZv[wv][64*s], sWf, Mf, R);
    const float4 rr = *(const float4*)(&R[lane*4]);
    rr0[s] = sigmoidf(rr.x);
    rr1[s] = sigmoidf(rr.y);
    rr2[s] = sigmoidf(rr.z);
    dens[s] = fmaxf(rr.w, 0.f);
  }

  float dd[3];
#pragma unroll
  for (int s = 0; s < 3; ++s) {
    const int i = lane + 64*s;
    const float td = (i == NZ-1) ? 1e10f : fmaxf(zn[s] - zc[s], 0.f);
    dd[s] = fminf(dens[s] * (td * dnorm), 1e4f);
  }

  float excl[3];
  float offset = 0.f;
#pragma unroll
  for (int s = 0; s < 3; ++s) {
    const float incl = wave_incl_scan(dd[s], lane);
    excl[s] = offset + incl - dd[s];
    offset += __shfl(incl, 63);
  }

  __syncthreads();   // sZv0 ready (wave 0 wrote it in its second coarse_pass)

  float aw = 0.f, awz = 0.f, ac0 = 0.f, ac1 = 0.f, ac2 = 0.f, awz0 = 0.f;
#pragma unroll
  for (int s = 0; s < 3; ++s) {
    const int i = lane + 64*s;
    const float wgt = (1.f - expf(-dd[s])) * expf(-excl[s]);
    aw   += wgt;
    awz  += wgt * zc[s];
    ac0  += wgt * rr0[s];
    ac1  += wgt * rr1[s];
    ac2  += wgt * rr2[s];
    awz0 += wgt * sZv0[i];
  }
  aw  = wave_sum(aw);  awz = wave_sum(awz); ac0 = wave_sum(ac0);
  ac1 = wave_sum(ac1); ac2 = wave_sum(ac2); awz0 = wave_sum(awz0);

  if (lane == 0) {
    const float bk0 = bkgd[0], bk1 = bkgd[1], bk2 = bkgd[2];
    const float o0x = origins[0], o0y = origins[1], o0z = origins[2];
    const float d0x = dirs[0],    d0y = dirs[1],    d0z = dirs[2];
    const float oma = 1.f - aw;
    float* o = out + (size_t)ray * 16 + 8;
    o[0] = ac0 + bk0 * oma;
    o[1] = ac1 + bk1 * oma;
    o[2] = ac2 + bk2 * oma;
    o[3] = awz;
    o[4] = aw;
    o[5] = aw * o0x + awz0 * d0x;
    o[6] = aw * o0y + awz0 * d0y;
    o[7] = aw * o0z + awz0 * d0z;
  }
}

extern "C" void kernel_launch(void* const* d_in, const int* in_sizes, int n_in,
                              void* d_out, int out_size, void* d_ws, size_t ws_size,
                              hipStream_t stream) {
  const float* origins = (const float*)d_in[0];
  const float* dirs    = (const float*)d_in[1];
  const float* nearp   = (const float*)d_in[2];
  const float* farp    = (const float*)d_in[3];
  const float* bkgd    = (const float*)d_in[4];
  const float* w1c  = (const float*)d_in[5];
  const float* b1c  = (const float*)d_in[6];
  const float* w2c  = (const float*)d_in[7];
  const float* b2c  = (const float*)d_in[8];
  const float* wrc  = (const float*)d_in[9];
  const float* brc  = (const float*)d_in[10];
  const float* wdc  = (const float*)d_in[11];
  const float* bdc  = (const float*)d_in[12];
  const float* w1f  = (const float*)d_in[13];
  const float* b1f  = (const float*)d_in[14];
  const float* w2f  = (const float*)d_in[15];
  const float* b2f_ = (const float*)d_in[16];
  const float* wrf  = (const float*)d_in[17];
  const float* brf  = (const float*)d_in[18];
  const float* wdf  = (const float*)d_in[19];
  const float* bdf  = (const float*)d_in[20];

  nerf_fused_kernel<<<NRAYS/4, 256, 0, stream>>>(
      origins, dirs, nearp, farp, bkgd,
      w1c, b1c, w2c, b2c, wrc, brc, wdc, bdc,
      w1f, b1f, w2f, b2f_, wrf, brf, wdf, bdf,
      (float*)d_out);
}

// Round 11
// 527.150 us; speedup vs baseline: 7.6448x; 1.0879x over previous
//
#include <hip/hip_runtime.h>
#include <math.h>

#define NRAYS 16384
#define NC    64
#define NF    128
#define NZ    192   // NC + NF
#define H     64

typedef __attribute__((ext_vector_type(8))) short bf16x8;  // 8 bf16 (4 VGPRs)
typedef __attribute__((ext_vector_type(4))) float f32x4;   // MFMA C/D
typedef __attribute__((ext_vector_type(4))) int   i32x4;

__device__ __forceinline__ float wave_incl_scan(float v, int lane) {
#pragma unroll
  for (int off = 1; off < 64; off <<= 1) {
    float n = __shfl_up(v, off);
    v = (lane >= off) ? v + n : v;
  }
  return v;
}

__device__ __forceinline__ float wave_incl_max_scan(float v, int lane) {
#pragma unroll
  for (int off = 1; off < 64; off <<= 1) {
    float n = __shfl_up(v, off);
    v = (lane >= off) ? fmaxf(v, n) : v;
  }
  return v;
}

__device__ __forceinline__ float wave_sum(float v) {
#pragma unroll
  for (int off = 32; off > 0; off >>= 1) v += __shfl_xor(v, off);
  return v;
}

// fp32 -> bf16 hi + bf16 lo (truncation split; 3-term MFMA has rel err ~2^-15).
__device__ __forceinline__ void split_bf16(float f, short& hi, short& lo) {
  unsigned u = __float_as_uint(f);
  hi = (short)(u >> 16);
  float rem = f - __uint_as_float(u & 0xFFFF0000u);   // exact
  lo = (short)(__float_as_uint(rem) >> 16);
}

__device__ __forceinline__ float sigmoidf(float x) {
  return 1.f / (1.f + expf(-x));
}

// Layer-1 weights in LDS — only read 16x per ray now (a/b precompute).
struct __align__(16) WLds {
  float W1b[H][4];   // {w1[0][k], w1[1][k], w1[2][k], b1[k]}
};

__device__ __forceinline__ void load_w1_lds(
    int tid, const float* __restrict__ w1, const float* __restrict__ b1,
    WLds& W)
{
  // UNSIGNED guard (R8 bug: negative tid corrupted the preceding LDS struct).
  if ((unsigned)tid < (unsigned)H) {
    int k = tid;
    W.W1b[k][0] = w1[0*H + k];
    W.W1b[k][1] = w1[1*H + k];
    W.W1b[k][2] = w1[2*H + k];
    W.W1b[k][3] = b1[k];
  }
}

// R11: x = o + z*d with o,d ray-constant  =>  h1_k = relu(a_k + z*b_k),
// a_k = o.w1[:,k]+b1[k], b_k = d.w1[:,k]. Per-lane registers for this lane's
// 16 k values kill ALL inner-loop LDS reads (64 ds_read_b128/batch in R10 —
// the LDS pipe was the binding resource at 12 waves/CU).
struct RayAB { float a[16]; float b[16]; };   // idx = kt*8 + j

__device__ __forceinline__ void compute_ray_ab(
    int lane, float ox, float oy, float oz, float dx, float dy, float dz,
    const WLds& W, RayAB& AB)
{
  const int quad = lane >> 4;
#pragma unroll
  for (int kt = 0; kt < 2; ++kt) {
#pragma unroll
    for (int j = 0; j < 8; ++j) {
      const int k = kt*32 + quad*8 + j;
      const float4 wv = *(const float4*)(&W.W1b[k][0]);
      AB.a[kt*8+j] = fmaf(ox, wv.x, fmaf(oy, wv.y, fmaf(oz, wv.z, wv.w)));
      AB.b[kt*8+j] = fmaf(dx, wv.x, fmaf(dy, wv.y, dz * wv.z));
    }
  }
}

// Per-wave register-resident weights for one MLP.
// 16x16x32 bf16 layouts (HW-verified, guide §3):
//   A[m][k]: m = lane&15, k = (lane>>4)*8 + j
//   B[k][n]: n = lane&15, k = (lane>>4)*8 + j
//   C/D[m][n]: n = lane&15, m = (lane>>4)*4 + reg
struct MfmaW {
  bf16x8 Bhi[2][4], Blo[2][4];  // w2 [kt][jt]
  float  whv[4][4];             // head weights [jt][c], k = jt*16 + n16
  float  hbown;                 // head bias for this lane's c = n16&3
  float  b2v[4];                // b2[jt*16 + n16]
};

__device__ __forceinline__ void load_mfma_weights(
    int lane,
    const float* __restrict__ w2, const float* __restrict__ b2,
    const float* __restrict__ wr, const float* __restrict__ br,
    const float* __restrict__ wd, const float* __restrict__ bd,
    MfmaW& M)
{
  const int quad = lane >> 4, n16 = lane & 15;
#pragma unroll
  for (int kt = 0; kt < 2; ++kt) {
#pragma unroll
    for (int jt = 0; jt < 4; ++jt) {
#pragma unroll
      for (int j = 0; j < 8; ++j) {
        const int k = kt*32 + quad*8 + j;
        short hi, lo;
        split_bf16(w2[k*H + jt*16 + n16], hi, lo);
        M.Bhi[kt][jt][j] = hi; M.Blo[kt][jt][j] = lo;
      }
    }
  }
#pragma unroll
  for (int jt = 0; jt < 4; ++jt) {
    const int k = jt*16 + n16;
    M.whv[jt][0] = wr[k*3 + 0];
    M.whv[jt][1] = wr[k*3 + 1];
    M.whv[jt][2] = wr[k*3 + 2];
    M.whv[jt][3] = wd[k];
  }
  const int c = n16 & 3;
  M.hbown = (c == 0) ? br[0] : (c == 1) ? br[1] : (c == 2) ? br[2] : bd[0];
#pragma unroll
  for (int jt = 0; jt < 4; ++jt) M.b2v[jt] = b2[jt*16 + n16];
}

// One 64-sample MLP batch for one ray (one wave). zsrc: 64 z-values in LDS.
// Layer 1: 1 fma + 1 max per element from RayAB registers (no LDS).
// Layer 2: split-bf16 MFMA. Head: in-lane fp32 + halving butterfly reduce.
// Output: R[sample*4 + c] (c: 0..2 rgb-logit, 3 density-logit), bias incl.
__device__ __forceinline__ void mlp_mfma_batch(
    int lane, const RayAB& AB,
    const float* __restrict__ zsrc, const MfmaW& M,
    float* __restrict__ R)
{
  const int quad = lane >> 4, n16 = lane & 15;
#pragma unroll 1   // rolled: prevents register blow-up (R5/R6 lesson)
  for (int mt = 0; mt < 4; ++mt) {
    const float z = zsrc[mt*16 + n16];
    f32x4 C[4];
#pragma unroll
    for (int jt = 0; jt < 4; ++jt)
      C[jt] = (f32x4){M.b2v[jt], M.b2v[jt], M.b2v[jt], M.b2v[jt]};
#pragma unroll
    for (int kt = 0; kt < 2; ++kt) {
      // h1 pair-wise with manual hi/lo word packing (3 int ops per word)
      i32x4 hip, lop;
#pragma unroll
      for (int j2 = 0; j2 < 4; ++j2) {
        const float h0 = fmaxf(fmaf(z, AB.b[kt*8+2*j2],   AB.a[kt*8+2*j2]),   0.f);
        const float h1 = fmaxf(fmaf(z, AB.b[kt*8+2*j2+1], AB.a[kt*8+2*j2+1]), 0.f);
        const unsigned u0 = __float_as_uint(h0), u1 = __float_as_uint(h1);
        hip[j2] = (int)((u0 >> 16) | (u1 & 0xFFFF0000u));
        const float r0 = h0 - __uint_as_float(u0 & 0xFFFF0000u);
        const float r1 = h1 - __uint_as_float(u1 & 0xFFFF0000u);
        lop[j2] = (int)((__float_as_uint(r0) >> 16) |
                        (__float_as_uint(r1) & 0xFFFF0000u));
      }
      union { i32x4 i; bf16x8 h; } uh, ul;
      uh.i = hip; ul.i = lop;
#pragma unroll
      for (int jt = 0; jt < 4; ++jt) {
        C[jt] = __builtin_amdgcn_mfma_f32_16x16x32_bf16(uh.h, M.Bhi[kt][jt], C[jt], 0, 0, 0);
        C[jt] = __builtin_amdgcn_mfma_f32_16x16x32_bf16(ul.h, M.Bhi[kt][jt], C[jt], 0, 0, 0);
        C[jt] = __builtin_amdgcn_mfma_f32_16x16x32_bf16(uh.h, M.Blo[kt][jt], C[jt], 0, 0, 0);
      }
    }
    // ---- head in fp32: P[r*4+c] = sum_jt relu(C[jt][r]) * whv[jt][c] ----
    float P[16];
#pragma unroll
    for (int r = 0; r < 4; ++r) {
#pragma unroll
      for (int c = 0; c < 4; ++c) P[r*4 + c] = 0.f;
#pragma unroll
      for (int jt = 0; jt < 4; ++jt) {
        const float h2v = fmaxf(C[jt][r], 0.f);
#pragma unroll
        for (int c = 0; c < 4; ++c)
          P[r*4 + c] = fmaf(h2v, M.whv[jt][c], P[r*4 + c]);
      }
    }
    // halving reduce across the 16 lanes of this quad-group; after 4 stages
    // lane n16 holds element i=n16 -> (m=4q+(n16>>2), c=n16&3)
    const bool b0 = (n16 & 1), b1 = (n16 & 2), b2_ = (n16 & 4), b3 = (n16 & 8);
    float Q[8];
#pragma unroll
    for (int s = 0; s < 8; ++s) {
      const float give = b0 ? P[2*s] : P[2*s+1];
      const float keep = b0 ? P[2*s+1] : P[2*s];
      Q[s] = keep + __shfl_xor(give, 1);
    }
    float U[4];
#pragma unroll
    for (int t = 0; t < 4; ++t) {
      const float give = b1 ? Q[2*t] : Q[2*t+1];
      const float keep = b1 ? Q[2*t+1] : Q[2*t];
      U[t] = keep + __shfl_xor(give, 2);
    }
    float V[2];
#pragma unroll
    for (int u = 0; u < 2; ++u) {
      const float give = b2_ ? U[2*u] : U[2*u+1];
      const float keep = b2_ ? U[2*u+1] : U[2*u];
      V[u] = keep + __shfl_xor(give, 4);
    }
    {
      const float give = b3 ? V[0] : V[1];
      const float keep = b3 ? V[1] : V[0];
      const float total = keep + __shfl_xor(give, 8);
      R[mt*64 + lane] = total + M.hbown;   // coalesced: addr = sample*4 + c
    }
  }
  __builtin_amdgcn_wave_barrier();     // R complete before readback
}

// Coarse pass for one ray, executed by ONE wave (wave-private LDS scratch).
__device__ __forceinline__ void coarse_pass(
    int ray, int lane,
    const float* __restrict__ origins, const float* __restrict__ dirs,
    const float* __restrict__ nearp, const float* __restrict__ farp,
    const float* __restrict__ bkgd,
    const WLds& W, const MfmaW& M, float* __restrict__ R,
    float* __restrict__ sT, float* __restrict__ sBins,
    float* __restrict__ sCdf, float* __restrict__ sZs,
    float* __restrict__ zdst, bool emit, float* __restrict__ out)
{
  const float nearv = nearp[ray];
  const float farv  = farp[ray];
  const float ox = origins[ray*3+0], oy = origins[ray*3+1], oz = origins[ray*3+2];
  const float dx = dirs[ray*3+0],    dy = dirs[ray*3+1],    dz = dirs[ray*3+2];

  RayAB AB;
  compute_ray_ab(lane, ox, oy, oz, dx, dy, dz, W, AB);

  const float u_i  = (float)lane / 63.0f;
  const float u_n  = (float)(lane + 1) / 63.0f;
  const float tv    = nearv * (1.f - u_i) + farv * u_i;
  const float tnext = nearv * (1.f - u_n) + farv * u_n;

  sT[lane] = tv;
  if (lane < NC-1) sBins[lane] = 0.5f * (tv + tnext);
  zdst[lane] = 0.f; zdst[lane+64] = 0.f; zdst[lane+128] = 0.f;
  __builtin_amdgcn_wave_barrier();     // sT ready for the batch

  mlp_mfma_batch(lane, AB, sT, M, R);
  const float4 rr = *(const float4*)(&R[lane*4]);
  const float rgb0 = sigmoidf(rr.x), rgb1 = sigmoidf(rr.y), rgb2 = sigmoidf(rr.z);
  const float dens = fmaxf(rr.w, 0.f);

  const float dnorm = sqrtf(dx*dx + dy*dy + dz*dz);
  const float tdist = (lane == NC-1) ? 1e10f : (tnext - tv);
  const float dd    = fminf(dens * (tdist * dnorm), 1e4f);
  const float incl  = wave_incl_scan(dd, lane);
  const float excl  = incl - dd;
  const float alpha = 1.f - expf(-dd);
  const float trans = expf(-excl);
  const float w     = alpha * trans;

  if (emit) {
    const float near0 = nearp[0], far0 = farp[0];
    const float t0v   = near0 * (1.f - u_i) + far0 * u_i;
    const float s_w   = wave_sum(w);
    const float s_wt  = wave_sum(w * tv);
    const float s_c0  = wave_sum(w * rgb0);
    const float s_c1  = wave_sum(w * rgb1);
    const float s_c2  = wave_sum(w * rgb2);
    const float s_wt0 = wave_sum(w * t0v);
    if (lane == 0) {
      const float bk0 = bkgd[0], bk1 = bkgd[1], bk2 = bkgd[2];
      const float o0x = origins[0], o0y = origins[1], o0z = origins[2];
      const float d0x = dirs[0],    d0y = dirs[1],    d0z = dirs[2];
      const float oma = 1.f - s_w;
      float* o = out + (size_t)ray * 16;
      o[0] = s_c0 + bk0 * oma;
      o[1] = s_c1 + bk1 * oma;
      o[2] = s_c2 + bk2 * oma;
      o[3] = s_wt;
      o[4] = s_w;
      o[5] = s_w * o0x + s_wt0 * d0x;
      o[6] = s_w * o0y + s_wt0 * d0y;
      o[7] = s_w * o0z + s_wt0 * d0z;
    }
  }

  // ---- PDF -> CDF (62 weights = w[1..62]) ----
  const float wnext = __shfl_down(w, 1);
  const float pw = (lane < NC-2) ? wnext : 0.f;
  const float ws_sum = wave_sum(pw);
  const float pad = fmaxf(1e-5f - ws_sum, 0.f);
  const float wsp = ws_sum + pad;
  const float pdf = (lane < NC-2) ? (pw + pad * (1.f/62.f)) / wsp : 0.f;
  float ip  = wave_incl_scan(pdf, lane);
  ip = wave_incl_max_scan(ip, lane);       // exact monotone
  if (lane < 61)  sCdf[lane+1] = fminf(ip, 1.f);
  if (lane == 61) sCdf[0]  = 0.f;
  if (lane == 62) sCdf[62] = 1.f;
  __builtin_amdgcn_wave_barrier();

  // ---- inverse-CDF: 128 samples, 2 per lane ----
  const float ustep = (1.0f - 1.1920929e-07f) / 127.0f;
#pragma unroll
  for (int r = 0; r < 2; ++r) {
    const int k = lane + 64*r;
    const float u = k * ustep;
    int lo = 0, hi = 61;
    while (lo < hi) {
      const int mid = (lo + hi + 1) >> 1;
      if (sCdf[mid] <= u) lo = mid; else hi = mid - 1;
    }
    const int J = lo;
    const float cg0 = sCdf[J],  cg1 = sCdf[J+1];
    const float bg0 = sBins[J], bg1 = sBins[J+1];
    const float denom = cg1 - cg0;
    const float num   = u - cg0;
    float tt;
    if (denom > 0.f) tt = fminf(fmaxf(num / denom, 0.f), 1.f);
    else             tt = (num > 0.f) ? 1.f : 0.f;
    sZs[k] = fmaf(tt, bg1 - bg0, bg0);
  }
  __builtin_amdgcn_wave_barrier();

  // ---- stable rank merge of sorted t (64) and z (128) into zdst (192) ----
  {
    int l = 0, r = NF;
    while (l < r) { const int m = (l + r) >> 1; if (sZs[m] < tv) l = m + 1; else r = m; }
    zdst[lane + l] = tv;
  }
#pragma unroll
  for (int r2 = 0; r2 < 2; ++r2) {
    const int k = lane + 64*r2;
    const float z = sZs[k];
    int l = 0, r = NC;
    while (l < r) { const int m = (l + r) >> 1; if (sT[m] <= z) l = m + 1; else r = m; }
    zdst[k + l] = z;
  }
  __builtin_amdgcn_wave_barrier();
}

// ---------------- Fused kernel: 4 waves = 4 rays per block, no global scratch
__global__ __launch_bounds__(256) void nerf_fused_kernel(
    const float* __restrict__ origins, const float* __restrict__ dirs,
    const float* __restrict__ nearp, const float* __restrict__ farp,
    const float* __restrict__ bkgd,
    const float* __restrict__ w1c, const float* __restrict__ b1c,
    const float* __restrict__ w2c, const float* __restrict__ b2c,
    const float* __restrict__ wrc, const float* __restrict__ brc,
    const float* __restrict__ wdc, const float* __restrict__ bdc,
    const float* __restrict__ w1f, const float* __restrict__ b1f,
    const float* __restrict__ w2f, const float* __restrict__ b2f_,
    const float* __restrict__ wrf, const float* __restrict__ brf,
    const float* __restrict__ wdf, const float* __restrict__ bdf,
    float* __restrict__ out)
{
  __shared__ WLds sWc, sWf;
  __shared__ float sT[4][NC];
  __shared__ float sBins[4][NC];
  __shared__ float sCdf[4][NC];
  __shared__ float sZs[4][NF];
  __shared__ float sZv[4][NZ];
  __shared__ float sZv0[NZ];                // ray 0's fine z row (quirk)
  __shared__ float sR[4][64*4];             // per-wave head logits

  const int tid  = threadIdx.x;
  const int wv   = tid >> 6;
  const int lane = tid & 63;
  const int ray  = blockIdx.x * 4 + wv;

  load_w1_lds(tid, w1c, b1c, sWc);
  load_w1_lds(tid - 64, w1f, b1f, sWf);     // threads 64..127 (unsigned guard)
  __syncthreads();

  float* R = sR[wv];

  // ---- coarse MLP weight frags (registers), coarse pass(es) ----
  {
    MfmaW Mc;
    load_mfma_weights(lane, w2c, b2c, wrc, brc, wdc, bdc, Mc);

    coarse_pass(ray, lane, origins, dirs, nearp, farp, bkgd,
                sWc, Mc, R,
                sT[wv], sBins[wv], sCdf[wv], sZs[wv], sZv[wv], true, out);

    if (wv == 0) {
      coarse_pass(0, lane, origins, dirs, nearp, farp, bkgd,
                  sWc, Mc, R,
                  sT[0], sBins[0], sCdf[0], sZs[0], sZv0, false, out);
    }
  }

  // ---- fine pass: 3 batches of 64 samples ----
  MfmaW Mf;
  load_mfma_weights(lane, w2f, b2f_, wrf, brf, wdf, bdf, Mf);

  const float ox = origins[ray*3+0], oy = origins[ray*3+1], oz = origins[ray*3+2];
  const float dx = dirs[ray*3+0],    dy = dirs[ray*3+1],    dz = dirs[ray*3+2];
  const float dnorm = sqrtf(dx*dx + dy*dy + dz*dz);

  RayAB ABf;
  compute_ray_ab(lane, ox, oy, oz, dx, dy, dz, sWf, ABf);

  float zc[3], zn[3];
#pragma unroll
  for (int s = 0; s < 3; ++s) {
    const int i = lane + 64*s;
    zc[s] = sZv[wv][i];
    zn[s] = (i < NZ-1) ? sZv[wv][i+1] : 0.f;
  }

  float rr0[3], rr1[3], rr2[3], dens[3];
#pragma unroll
  for (int s = 0; s < 3; ++s) {
    mlp_mfma_batch(lane, ABf, &sZv[wv][64*s], Mf, R);
    const float4 rr = *(const float4*)(&R[lane*4]);
    rr0[s] = sigmoidf(rr.x);
    rr1[s] = sigmoidf(rr.y);
    rr2[s] = sigmoidf(rr.z);
    dens[s] = fmaxf(rr.w, 0.f);
  }

  float dd[3];
#pragma unroll
  for (int s = 0; s < 3; ++s) {
    const int i = lane + 64*s;
    const float td = (i == NZ-1) ? 1e10f : fmaxf(zn[s] - zc[s], 0.f);
    dd[s] = fminf(dens[s] * (td * dnorm), 1e4f);
  }

  float excl[3];
  float offset = 0.f;
#pragma unroll
  for (int s = 0; s < 3; ++s) {
    const float incl = wave_incl_scan(dd[s], lane);
    excl[s] = offset + incl - dd[s];
    offset += __shfl(incl, 63);
  }

  __syncthreads();   // sZv0 ready (wave 0 wrote it in its second coarse_pass)

  float aw = 0.f, awz = 0.f, ac0 = 0.f, ac1 = 0.f, ac2 = 0.f, awz0 = 0.f;
#pragma unroll
  for (int s = 0; s < 3; ++s) {
    const int i = lane + 64*s;
    const float wgt = (1.f - expf(-dd[s])) * expf(-excl[s]);
    aw   += wgt;
    awz  += wgt * zc[s];
    ac0  += wgt * rr0[s];
    ac1  += wgt * rr1[s];
    ac2  += wgt * rr2[s];
    awz0 += wgt * sZv0[i];
  }
  aw  = wave_sum(aw);  awz = wave_sum(awz); ac0 = wave_sum(ac0);
  ac1 = wave_sum(ac1); ac2 = wave_sum(ac2); awz0 = wave_sum(awz0);

  if (lane == 0) {
    const float bk0 = bkgd[0], bk1 = bkgd[1], bk2 = bkgd[2];
    const float o0x = origins[0], o0y = origins[1], o0z = origins[2];
    const float d0x = dirs[0],    d0y = dirs[1],    d0z = dirs[2];
    const float oma = 1.f - aw;
    float* o = out + (size_t)ray * 16 + 8;
    o[0] = ac0 + bk0 * oma;
    o[1] = ac1 + bk1 * oma;
    o[2] = ac2 + bk2 * oma;
    o[3] = awz;
    o[4] = aw;
    o[5] = aw * o0x + awz0 * d0x;
    o[6] = aw * o0y + awz0 * d0y;
    o[7] = aw * o0z + awz0 * d0z;
  }
}

extern "C" void kernel_launch(void* const* d_in, const int* in_sizes, int n_in,
                              void* d_out, int out_size, void* d_ws, size_t ws_size,
                              hipStream_t stream) {
  const float* origins = (const float*)d_in[0];
  const float* dirs    = (const float*)d_in[1];
  const float* nearp   = (const float*)d_in[2];
  const float* farp    = (const float*)d_in[3];
  const float* bkgd    = (const float*)d_in[4];
  const float* w1c  = (const float*)d_in[5];
  const float* b1c  = (const float*)d_in[6];
  const float* w2c  = (const float*)d_in[7];
  const float* b2c  = (const float*)d_in[8];
  const float* wrc  = (const float*)d_in[9];
  const float* brc  = (const float*)d_in[10];
  const float* wdc  = (const float*)d_in[11];
  const float* bdc  = (const float*)d_in[12];
  const float* w1f  = (const float*)d_in[13];
  const float* b1f  = (const float*)d_in[14];
  const float* w2f  = (const float*)d_in[15];
  const float* b2f_ = (const float*)d_in[16];
  const float* wrf  = (const float*)d_in[17];
  const float* brf  = (const float*)d_in[18];
  const float* wdf  = (const float*)d_in[19];
  const float* bdf  = (const float*)d_in[20];

  nerf_fused_kernel<<<NRAYS/4, 256, 0, stream>>>(
      origins, dirs, nearp, farp, bkgd,
      w1c, b1c, w2c, b2c, wrc, brc, wdc, bdc,
      w1f, b1f, w2f, b2f_, wrf, brf, wdf, bdf,
      (float*)d_out);
}

// Round 12
// 439.764 us; speedup vs baseline: 9.1639x; 1.1987x over previous
//
#include <hip/hip_runtime.h>
#include <math.h>

#define NRAYS 16384
#define NC    64
#define NF    128
#define NZ    192   // NC + NF
#define H     64

typedef __attribute__((ext_vector_type(8))) short bf16x8;  // 8 bf16 (4 VGPRs)
typedef __attribute__((ext_vector_type(4))) float f32x4;   // MFMA C/D
typedef __attribute__((ext_vector_type(4))) int   i32x4;

__device__ __forceinline__ float wave_incl_scan(float v, int lane) {
#pragma unroll
  for (int off = 1; off < 64; off <<= 1) {
    float n = __shfl_up(v, off);
    v = (lane >= off) ? v + n : v;
  }
  return v;
}

__device__ __forceinline__ float wave_incl_max_scan(float v, int lane) {
#pragma unroll
  for (int off = 1; off < 64; off <<= 1) {
    float n = __shfl_up(v, off);
    v = (lane >= off) ? fmaxf(v, n) : v;
  }
  return v;
}

__device__ __forceinline__ float wave_sum(float v) {
#pragma unroll
  for (int off = 32; off > 0; off >>= 1) v += __shfl_xor(v, off);
  return v;
}

// fp32 -> bf16 hi + bf16 lo (truncation split; 3-term MFMA has rel err ~2^-15).
__device__ __forceinline__ void split_bf16(float f, short& hi, short& lo) {
  unsigned u = __float_as_uint(f);
  hi = (short)(u >> 16);
  float rem = f - __uint_as_float(u & 0xFFFF0000u);   // exact
  lo = (short)(__float_as_uint(rem) >> 16);
}

__device__ __forceinline__ float sigmoidf(float x) {
  return 1.f / (1.f + expf(-x));
}

// Layer-1 weights in LDS — read 16x per ray (a/b precompute).
struct __align__(16) WLds {
  float W1b[H][4];   // {w1[0][k], w1[1][k], w1[2][k], b1[k]}
};

// h1_k = relu(a_k + z*b_k); a,b per-ray constants in registers (R11 win).
struct RayAB { float a[16]; float b[16]; };   // idx = kt*8 + j

__device__ __forceinline__ void compute_ray_ab(
    int lane, float ox, float oy, float oz, float dx, float dy, float dz,
    const WLds& W, RayAB& AB)
{
  const int quad = lane >> 4;
#pragma unroll
  for (int kt = 0; kt < 2; ++kt) {
#pragma unroll
    for (int j = 0; j < 8; ++j) {
      const int k = kt*32 + quad*8 + j;
      const float4 wv = *(const float4*)(&W.W1b[k][0]);
      AB.a[kt*8+j] = fmaf(ox, wv.x, fmaf(oy, wv.y, fmaf(oz, wv.z, wv.w)));
      AB.b[kt*8+j] = fmaf(dx, wv.x, fmaf(dy, wv.y, dz * wv.z));
    }
  }
}

// Register-resident w2 fragments only (R12: whv/b2 moved to LDS, -20 VGPR).
// 16x16x32 bf16 layouts (HW-verified, guide §3).
struct MfmaW {
  bf16x8 Bhi[2][4], Blo[2][4];  // w2 [kt][jt]
  float  hbown;                 // head bias for this lane's c = n16&3
};

__device__ __forceinline__ void load_mfma_weights(
    int lane,
    const float* __restrict__ w2,
    const float* __restrict__ br, const float* __restrict__ bd,
    MfmaW& M)
{
  const int quad = lane >> 4, n16 = lane & 15;
#pragma unroll
  for (int kt = 0; kt < 2; ++kt) {
#pragma unroll
    for (int jt = 0; jt < 4; ++jt) {
#pragma unroll
      for (int j = 0; j < 8; ++j) {
        const int k = kt*32 + quad*8 + j;
        short hi, lo;
        split_bf16(w2[k*H + jt*16 + n16], hi, lo);
        M.Bhi[kt][jt][j] = hi; M.Blo[kt][jt][j] = lo;
      }
    }
  }
  const int c = n16 & 3;
  M.hbown = (c == 0) ? br[0] : (c == 1) ? br[1] : (c == 2) ? br[2] : bd[0];
}

// One 64-sample MLP batch. Layer1: regs. Layer2: split-bf16 MFMA.
// Head: in-lane fp32 (weights from LDS sHW[k][c], 2-way-conflict b128) +
// halving butterfly. Output R[sample*4 + c], bias included.
__device__ __forceinline__ void mlp_mfma_batch(
    int lane, const RayAB& AB,
    const float* __restrict__ zsrc, const MfmaW& M,
    const float (*__restrict__ sHW)[4], const float* __restrict__ sB2,
    float* __restrict__ R)
{
  const int quad = lane >> 4, n16 = lane & 15;
  // b2 per-lane init values (wave-invariant, from LDS once per batch)
  float b2q[4];
#pragma unroll
  for (int jt = 0; jt < 4; ++jt) b2q[jt] = sB2[jt*16 + n16];
#pragma unroll 1   // rolled: prevents register blow-up (R5/R6 lesson)
  for (int mt = 0; mt < 4; ++mt) {
    const float z = zsrc[mt*16 + n16];
    f32x4 C[4];
#pragma unroll
    for (int jt = 0; jt < 4; ++jt)
      C[jt] = (f32x4){b2q[jt], b2q[jt], b2q[jt], b2q[jt]};
#pragma unroll
    for (int kt = 0; kt < 2; ++kt) {
      i32x4 hip, lop;
#pragma unroll
      for (int j2 = 0; j2 < 4; ++j2) {
        const float h0 = fmaxf(fmaf(z, AB.b[kt*8+2*j2],   AB.a[kt*8+2*j2]),   0.f);
        const float h1 = fmaxf(fmaf(z, AB.b[kt*8+2*j2+1], AB.a[kt*8+2*j2+1]), 0.f);
        const unsigned u0 = __float_as_uint(h0), u1 = __float_as_uint(h1);
        hip[j2] = (int)((u0 >> 16) | (u1 & 0xFFFF0000u));
        const float r0 = h0 - __uint_as_float(u0 & 0xFFFF0000u);
        const float r1 = h1 - __uint_as_float(u1 & 0xFFFF0000u);
        lop[j2] = (int)((__float_as_uint(r0) >> 16) |
                        (__float_as_uint(r1) & 0xFFFF0000u));
      }
      union { i32x4 i; bf16x8 h; } uh, ul;
      uh.i = hip; ul.i = lop;
#pragma unroll
      for (int jt = 0; jt < 4; ++jt) {
        C[jt] = __builtin_amdgcn_mfma_f32_16x16x32_bf16(uh.h, M.Bhi[kt][jt], C[jt], 0, 0, 0);
        C[jt] = __builtin_amdgcn_mfma_f32_16x16x32_bf16(ul.h, M.Bhi[kt][jt], C[jt], 0, 0, 0);
        C[jt] = __builtin_amdgcn_mfma_f32_16x16x32_bf16(uh.h, M.Blo[kt][jt], C[jt], 0, 0, 0);
      }
    }
    // ---- head: P[r*4+c] = sum_jt relu(C[jt][r]) * sHW[jt*16+n16][c] ----
    float4 hw[4];
#pragma unroll
    for (int jt = 0; jt < 4; ++jt)
      hw[jt] = *(const float4*)(&sHW[jt*16 + n16][0]);
    float P[16];
#pragma unroll
    for (int r = 0; r < 4; ++r) {
#pragma unroll
      for (int c = 0; c < 4; ++c) P[r*4 + c] = 0.f;
#pragma unroll
      for (int jt = 0; jt < 4; ++jt) {
        const float h2v = fmaxf(C[jt][r], 0.f);
        P[r*4 + 0] = fmaf(h2v, hw[jt].x, P[r*4 + 0]);
        P[r*4 + 1] = fmaf(h2v, hw[jt].y, P[r*4 + 1]);
        P[r*4 + 2] = fmaf(h2v, hw[jt].z, P[r*4 + 2]);
        P[r*4 + 3] = fmaf(h2v, hw[jt].w, P[r*4 + 3]);
      }
    }
    // halving reduce across 16 lanes; lane n16 ends with (m=4q+(n16>>2), c=n16&3)
    const bool b0 = (n16 & 1), b1 = (n16 & 2), b2_ = (n16 & 4), b3 = (n16 & 8);
    float Q[8];
#pragma unroll
    for (int s = 0; s < 8; ++s) {
      const float give = b0 ? P[2*s] : P[2*s+1];
      const float keep = b0 ? P[2*s+1] : P[2*s];
      Q[s] = keep + __shfl_xor(give, 1);
    }
    float U[4];
#pragma unroll
    for (int t = 0; t < 4; ++t) {
      const float give = b1 ? Q[2*t] : Q[2*t+1];
      const float keep = b1 ? Q[2*t+1] : Q[2*t];
      U[t] = keep + __shfl_xor(give, 2);
    }
    float V[2];
#pragma unroll
    for (int u = 0; u < 2; ++u) {
      const float give = b2_ ? U[2*u] : U[2*u+1];
      const float keep = b2_ ? U[2*u+1] : U[2*u];
      V[u] = keep + __shfl_xor(give, 4);
    }
    {
      const float give = b3 ? V[0] : V[1];
      const float keep = b3 ? V[1] : V[0];
      const float total = keep + __shfl_xor(give, 8);
      R[mt*64 + lane] = total + M.hbown;   // coalesced: addr = sample*4 + c
    }
  }
  __builtin_amdgcn_wave_barrier();     // R complete before readback
}

// Coarse pass for one ray, ONE wave, wave-private LDS scratch.
__device__ __forceinline__ void coarse_pass(
    int ray, int lane,
    const float* __restrict__ origins, const float* __restrict__ dirs,
    const float* __restrict__ nearp, const float* __restrict__ farp,
    const float* __restrict__ bkgd,
    const WLds& W, const MfmaW& M,
    const float (*__restrict__ sHW)[4], const float* __restrict__ sB2,
    float* __restrict__ R,
    float* __restrict__ sT, float* __restrict__ sBins,
    float* __restrict__ sCdf, float* __restrict__ sZs,
    float* __restrict__ zdst, bool emit, float* __restrict__ out)
{
  const float nearv = nearp[ray];
  const float farv  = farp[ray];
  const float ox = origins[ray*3+0], oy = origins[ray*3+1], oz = origins[ray*3+2];
  const float dx = dirs[ray*3+0],    dy = dirs[ray*3+1],    dz = dirs[ray*3+2];

  RayAB AB;
  compute_ray_ab(lane, ox, oy, oz, dx, dy, dz, W, AB);

  const float u_i  = (float)lane / 63.0f;
  const float u_n  = (float)(lane + 1) / 63.0f;
  const float tv    = nearv * (1.f - u_i) + farv * u_i;
  const float tnext = nearv * (1.f - u_n) + farv * u_n;

  sT[lane] = tv;
  if (lane < NC-1) sBins[lane] = 0.5f * (tv + tnext);
  zdst[lane] = 0.f; zdst[lane+64] = 0.f; zdst[lane+128] = 0.f;
  __builtin_amdgcn_wave_barrier();     // sT ready for the batch

  mlp_mfma_batch(lane, AB, sT, M, sHW, sB2, R);
  const float4 rr = *(const float4*)(&R[lane*4]);
  const float rgb0 = sigmoidf(rr.x), rgb1 = sigmoidf(rr.y), rgb2 = sigmoidf(rr.z);
  const float dens = fmaxf(rr.w, 0.f);

  const float dnorm = sqrtf(dx*dx + dy*dy + dz*dz);
  const float tdist = (lane == NC-1) ? 1e10f : (tnext - tv);
  const float dd    = fminf(dens * (tdist * dnorm), 1e4f);
  const float incl  = wave_incl_scan(dd, lane);
  const float excl  = incl - dd;
  const float alpha = 1.f - expf(-dd);
  const float trans = expf(-excl);
  const float w     = alpha * trans;

  if (emit) {
    const float near0 = nearp[0], far0 = farp[0];
    const float t0v   = near0 * (1.f - u_i) + far0 * u_i;
    const float s_w   = wave_sum(w);
    const float s_wt  = wave_sum(w * tv);
    const float s_c0  = wave_sum(w * rgb0);
    const float s_c1  = wave_sum(w * rgb1);
    const float s_c2  = wave_sum(w * rgb2);
    const float s_wt0 = wave_sum(w * t0v);
    if (lane == 0) {
      const float bk0 = bkgd[0], bk1 = bkgd[1], bk2 = bkgd[2];
      const float o0x = origins[0], o0y = origins[1], o0z = origins[2];
      const float d0x = dirs[0],    d0y = dirs[1],    d0z = dirs[2];
      const float oma = 1.f - s_w;
      float* o = out + (size_t)ray * 16;
      o[0] = s_c0 + bk0 * oma;
      o[1] = s_c1 + bk1 * oma;
      o[2] = s_c2 + bk2 * oma;
      o[3] = s_wt;
      o[4] = s_w;
      o[5] = s_w * o0x + s_wt0 * d0x;
      o[6] = s_w * o0y + s_wt0 * d0y;
      o[7] = s_w * o0z + s_wt0 * d0z;
    }
  }

  // ---- PDF -> CDF (62 weights = w[1..62]) ----
  const float wnext = __shfl_down(w, 1);
  const float pw = (lane < NC-2) ? wnext : 0.f;
  const float ws_sum = wave_sum(pw);
  const float pad = fmaxf(1e-5f - ws_sum, 0.f);
  const float wsp = ws_sum + pad;
  const float pdf = (lane < NC-2) ? (pw + pad * (1.f/62.f)) / wsp : 0.f;
  float ip  = wave_incl_scan(pdf, lane);
  ip = wave_incl_max_scan(ip, lane);       // exact monotone
  if (lane < 61)  sCdf[lane+1] = fminf(ip, 1.f);
  if (lane == 61) sCdf[0]  = 0.f;
  if (lane == 62) sCdf[62] = 1.f;
  __builtin_amdgcn_wave_barrier();

  // ---- inverse-CDF: 128 samples, 2 per lane ----
  const float ustep = (1.0f - 1.1920929e-07f) / 127.0f;
#pragma unroll
  for (int r = 0; r < 2; ++r) {
    const int k = lane + 64*r;
    const float u = k * ustep;
    int lo = 0, hi = 61;
    while (lo < hi) {
      const int mid = (lo + hi + 1) >> 1;
      if (sCdf[mid] <= u) lo = mid; else hi = mid - 1;
    }
    const int J = lo;
    const float cg0 = sCdf[J],  cg1 = sCdf[J+1];
    const float bg0 = sBins[J], bg1 = sBins[J+1];
    const float denom = cg1 - cg0;
    const float num   = u - cg0;
    float tt;
    if (denom > 0.f) tt = fminf(fmaxf(num / denom, 0.f), 1.f);
    else             tt = (num > 0.f) ? 1.f : 0.f;
    sZs[k] = fmaf(tt, bg1 - bg0, bg0);
  }
  __builtin_amdgcn_wave_barrier();

  // ---- stable rank merge of sorted t (64) and z (128) into zdst (192) ----
  {
    int l = 0, r = NF;
    while (l < r) { const int m = (l + r) >> 1; if (sZs[m] < tv) l = m + 1; else r = m; }
    zdst[lane + l] = tv;
  }
#pragma unroll
  for (int r2 = 0; r2 < 2; ++r2) {
    const int k = lane + 64*r2;
    const float z = sZs[k];
    int l = 0, r = NC;
    while (l < r) { const int m = (l + r) >> 1; if (sT[m] <= z) l = m + 1; else r = m; }
    zdst[k + l] = z;
  }
  __builtin_amdgcn_wave_barrier();
}

// -------- Kernel 1: ONE block, ONE wave — ray 0's merged z row -> d_ws ------
__global__ __launch_bounds__(64) void nerf_z0_kernel(
    const float* __restrict__ origins, const float* __restrict__ dirs,
    const float* __restrict__ nearp, const float* __restrict__ farp,
    const float* __restrict__ w1c, const float* __restrict__ b1c,
    const float* __restrict__ w2c, const float* __restrict__ b2c,
    const float* __restrict__ wrc, const float* __restrict__ brc,
    const float* __restrict__ wdc, const float* __restrict__ bdc,
    float* __restrict__ gz0)
{
  __shared__ WLds sW;
  __shared__ float sHW[H][4];
  __shared__ float sB2[H];
  __shared__ float sT[NC], sBins[NC], sCdf[NC], sZs[NF], sZv0[NZ];
  __shared__ float sR[256];

  const int lane = threadIdx.x;
  {
    const int k = lane;
    sW.W1b[k][0] = w1c[0*H + k];
    sW.W1b[k][1] = w1c[1*H + k];
    sW.W1b[k][2] = w1c[2*H + k];
    sW.W1b[k][3] = b1c[k];
    sHW[k][0] = wrc[k*3 + 0];
    sHW[k][1] = wrc[k*3 + 1];
    sHW[k][2] = wrc[k*3 + 2];
    sHW[k][3] = wdc[k];
    sB2[k]    = b2c[k];
  }
  __syncthreads();

  MfmaW Mc;
  load_mfma_weights(lane, w2c, brc, bdc, Mc);

  coarse_pass(0, lane, origins, dirs, nearp, farp, /*bkgd*/nullptr,
              sW, Mc, sHW, sB2, sR, sT, sBins, sCdf, sZs, sZv0,
              /*emit=*/false, /*out=*/nullptr);

#pragma unroll
  for (int s = 0; s < 3; ++s) gz0[lane + 64*s] = sZv0[lane + 64*s];
}

// -------- Kernel 2: 4 waves = 4 rays per block; z0 row read from d_ws -------
__global__ __launch_bounds__(256) void nerf_fused_kernel(
    const float* __restrict__ origins, const float* __restrict__ dirs,
    const float* __restrict__ nearp, const float* __restrict__ farp,
    const float* __restrict__ bkgd,
    const float* __restrict__ w1c, const float* __restrict__ b1c,
    const float* __restrict__ w2c, const float* __restrict__ b2c,
    const float* __restrict__ wrc, const float* __restrict__ brc,
    const float* __restrict__ wdc, const float* __restrict__ bdc,
    const float* __restrict__ w1f, const float* __restrict__ b1f,
    const float* __restrict__ w2f, const float* __restrict__ b2f_,
    const float* __restrict__ wrf, const float* __restrict__ brf,
    const float* __restrict__ wdf, const float* __restrict__ bdf,
    const float* __restrict__ gz0, float* __restrict__ out)
{
  __shared__ WLds sWc, sWf;
  __shared__ float sHWc[H][4], sHWf[H][4];
  __shared__ float sB2c[H], sB2f[H];
  __shared__ float sT[4][NC];
  __shared__ float sBins[4][NC];
  __shared__ float sCdf[4][NC];
  __shared__ float sZs[4][NF];
  __shared__ float sZv[4][NZ];
  __shared__ float sZv0[NZ];                // ray 0's fine z row (quirk)
  __shared__ float sR[4][3*256];            // per-wave logits, 3 fine buffers

  const int tid  = threadIdx.x;
  const int wv   = tid >> 6;
  const int lane = tid & 63;
  const int ray  = blockIdx.x * 4 + wv;

  if (tid < 64) {
    const int k = tid;
    sWc.W1b[k][0] = w1c[0*H + k];
    sWc.W1b[k][1] = w1c[1*H + k];
    sWc.W1b[k][2] = w1c[2*H + k];
    sWc.W1b[k][3] = b1c[k];
    sHWc[k][0] = wrc[k*3+0]; sHWc[k][1] = wrc[k*3+1];
    sHWc[k][2] = wrc[k*3+2]; sHWc[k][3] = wdc[k];
    sB2c[k] = b2c[k];
  } else if (tid < 128) {
    const int k = tid - 64;
    sWf.W1b[k][0] = w1f[0*H + k];
    sWf.W1b[k][1] = w1f[1*H + k];
    sWf.W1b[k][2] = w1f[2*H + k];
    sWf.W1b[k][3] = b1f[k];
    sHWf[k][0] = wrf[k*3+0]; sHWf[k][1] = wrf[k*3+1];
    sHWf[k][2] = wrf[k*3+2]; sHWf[k][3] = wdf[k];
    sB2f[k] = b2f_[k];
  }
  if (tid < NZ) sZv0[tid] = gz0[tid];       // z0 row from kernel 1
  __syncthreads();

  float* R = sR[wv];

  // ---- coarse pass (own ray only — no per-block ray-0 recompute) ----
  {
    MfmaW Mc;
    load_mfma_weights(lane, w2c, brc, bdc, Mc);
    coarse_pass(ray, lane, origins, dirs, nearp, farp, bkgd,
                sWc, Mc, sHWc, sB2c, R,
                sT[wv], sBins[wv], sCdf[wv], sZs[wv], sZv[wv], true, out);
  }

  // ---- fine pass: 3 batches of 64 samples, separate R buffers ----
  MfmaW Mf;
  load_mfma_weights(lane, w2f, brf, bdf, Mf);

  const float ox = origins[ray*3+0], oy = origins[ray*3+1], oz = origins[ray*3+2];
  const float dx = dirs[ray*3+0],    dy = dirs[ray*3+1],    dz = dirs[ray*3+2];
  const float dnorm = sqrtf(dx*dx + dy*dy + dz*dz);

  RayAB ABf;
  compute_ray_ab(lane, ox, oy, oz, dx, dy, dz, sWf, ABf);

#pragma unroll
  for (int s = 0; s < 3; ++s)
    mlp_mfma_batch(lane, ABf, &sZv[wv][64*s], Mf, sHWf, sB2f, R + s*256);

  float dd[3];
#pragma unroll
  for (int s = 0; s < 3; ++s) {
    const int i = lane + 64*s;
    const float dens = fmaxf(R[s*256 + lane*4 + 3], 0.f);
    const float zcv = sZv[wv][i];
    const float znv = (i < NZ-1) ? sZv[wv][i+1] : 0.f;
    const float td = (i == NZ-1) ? 1e10f : fmaxf(znv - zcv, 0.f);
    dd[s] = fminf(dens * (td * dnorm), 1e4f);
  }

  float excl[3];
  float offset = 0.f;
#pragma unroll
  for (int s = 0; s < 3; ++s) {
    const float incl = wave_incl_scan(dd[s], lane);
    excl[s] = offset + incl - dd[s];
    offset += __shfl(incl, 63);
  }

  float aw = 0.f, awz = 0.f, ac0 = 0.f, ac1 = 0.f, ac2 = 0.f, awz0 = 0.f;
#pragma unroll
  for (int s = 0; s < 3; ++s) {
    const int i = lane + 64*s;
    const float4 rr = *(const float4*)(&R[s*256 + lane*4]);
    const float wgt = (1.f - expf(-dd[s])) * expf(-excl[s]);
    aw   += wgt;
    awz  += wgt * sZv[wv][i];
    ac0  += wgt * sigmoidf(rr.x);
    ac1  += wgt * sigmoidf(rr.y);
    ac2  += wgt * sigmoidf(rr.z);
    awz0 += wgt * sZv0[i];
  }
  aw  = wave_sum(aw);  awz = wave_sum(awz); ac0 = wave_sum(ac0);
  ac1 = wave_sum(ac1); ac2 = wave_sum(ac2); awz0 = wave_sum(awz0);

  if (lane == 0) {
    const float bk0 = bkgd[0], bk1 = bkgd[1], bk2 = bkgd[2];
    const float o0x = origins[0], o0y = origins[1], o0z = origins[2];
    const float d0x = dirs[0],    d0y = dirs[1],    d0z = dirs[2];
    const float oma = 1.f - aw;
    float* o = out + (size_t)ray * 16 + 8;
    o[0] = ac0 + bk0 * oma;
    o[1] = ac1 + bk1 * oma;
    o[2] = ac2 + bk2 * oma;
    o[3] = awz;
    o[4] = aw;
    o[5] = aw * o0x + awz0 * d0x;
    o[6] = aw * o0y + awz0 * d0y;
    o[7] = aw * o0z + awz0 * d0z;
  }
}

extern "C" void kernel_launch(void* const* d_in, const int* in_sizes, int n_in,
                              void* d_out, int out_size, void* d_ws, size_t ws_size,
                              hipStream_t stream) {
  const float* origins = (const float*)d_in[0];
  const float* dirs    = (const float*)d_in[1];
  const float* nearp   = (const float*)d_in[2];
  const float* farp    = (const float*)d_in[3];
  const float* bkgd    = (const float*)d_in[4];
  const float* w1c  = (const float*)d_in[5];
  const float* b1c  = (const float*)d_in[6];
  const float* w2c  = (const float*)d_in[7];
  const float* b2c  = (const float*)d_in[8];
  const float* wrc  = (const float*)d_in[9];
  const float* brc  = (const float*)d_in[10];
  const float* wdc  = (const float*)d_in[11];
  const float* bdc  = (const float*)d_in[12];
  const float* w1f  = (const float*)d_in[13];
  const float* b1f  = (const float*)d_in[14];
  const float* w2f  = (const float*)d_in[15];
  const float* b2f_ = (const float*)d_in[16];
  const float* wrf  = (const float*)d_in[17];
  const float* brf  = (const float*)d_in[18];
  const float* wdf  = (const float*)d_in[19];
  const float* bdf  = (const float*)d_in[20];

  float* gz0 = (float*)d_ws;   // 192 floats = 768 B of scratch

  nerf_z0_kernel<<<1, 64, 0, stream>>>(
      origins, dirs, nearp, farp,
      w1c, b1c, w2c, b2c, wrc, brc, wdc, bdc, gz0);

  nerf_fused_kernel<<<NRAYS/4, 256, 0, stream>>>(
      origins, dirs, nearp, farp, bkgd,
      w1c, b1c, w2c, b2c, wrc, brc, wdc, bdc,
      w1f, b1f, w2f, b2f_, wrf, brf, wdf, bdf,
      gz0, (float*)d_out);
}